// Round 18
// baseline (1156.107 us; speedup 1.0000x reference)
//
#include <hip/hip_runtime.h>
#include <hip/hip_bf16.h>

// Transformer forward, MI355X gfx950.
// Inputs/outputs are FLOAT32 (per reference). bf16 is used only as the MFMA
// compute format; residual stream, LN, softmax, biases, logits all f32.
// Workspace layout (bytes):
//   x     f32 [2048][1024]   @ 0      (8 MB)   residual stream
//   h     bf16[2048][1024]   @ 8 MB   (4 MB)   LN outputs
//   qkv   bf16[2048][3072]   @ 12 MB  (12 MB)
//   v_t   bf16[1024][2048]   @ 24 MB  (4 MB)   V transposed for attention
//   attn  bf16[2048][1024]   @ 28 MB  (4 MB)
//   ffn   bf16[2048][4096]   @ 32 MB  (16 MB)
//   wT    bf16 (<=8 MB)      @ 48 MB  (8 MB)   transposed+converted weights
//   b3    f32 [4][3072]      @ 56 MB  (48 KB)  all-layer qkv bias
//   wteb  bf16[50257][1024]  @ 57 MB  (103 MB) bf16 copy of wte (if ws fits)
//
// Round 11/12: per-WAVE acc must stay <= 64 regs (8-wave fat tiles).
// Round 16/17: co-resident blocks c and c+256 share a CU -> attention uses
// COMPLEMENTARY qt pairing (p with 15-p) => 17 tile-units per CU, 8 waves/CU.
// Round 18: qkv GEMM at BM=64 -> 768 blocks = exactly 3/CU (was 1.5/CU with
// a 33% idle tail).

typedef unsigned short u16;
typedef unsigned int u32;
typedef __attribute__((ext_vector_type(8))) short bf16x8;   // 8 bf16 = 4 VGPR
typedef __attribute__((ext_vector_type(4))) float f32x4;

#define DEVINL static __device__ __forceinline__
#define WAITVM(N) asm volatile("s_waitcnt vmcnt(" #N ")" ::: "memory")

DEVINL u16 f2bf(float f){ __hip_bfloat16 h = __float2bfloat16(f); return *reinterpret_cast<u16*>(&h); }

DEVINL bf16x8 cvt8(float4 a, float4 b){
  bf16x8 r;
  r[0] = (short)f2bf(a.x); r[1] = (short)f2bf(a.y);
  r[2] = (short)f2bf(a.z); r[3] = (short)f2bf(a.w);
  r[4] = (short)f2bf(b.x); r[5] = (short)f2bf(b.y);
  r[6] = (short)f2bf(b.z); r[7] = (short)f2bf(b.w);
  return r;
}

DEVINL void gload16(const u16* g, u16* l){
  // async global->LDS: per-lane GLOBAL source, wave-uniform LDS base + lane*16
  __builtin_amdgcn_global_load_lds((const __attribute__((address_space(1))) void*)g,
                                   (__attribute__((address_space(3))) void*)l, 16, 0, 0);
}

// ---------------- f32 -> bf16 bulk convert (8 elems/lane) --------------------
__global__ __launch_bounds__(256) void cvt_bf16_kernel(const float* __restrict__ src,
    u16* __restrict__ dst, int n8){
  int i = blockIdx.x*256 + threadIdx.x;
  if (i >= n8) return;
  const float4* p = (const float4*)(src + (size_t)i*8);
  float4 a = p[0], b = p[1];
  *(bf16x8*)(dst + (size_t)i*8) = cvt8(a, b);
}

// ---------------- embedding gather: x[m][:] = wte[tok[m]][:] (f32 copy) ------
__global__ __launch_bounds__(256) void embed_kernel(const int* __restrict__ tok,
    const float* __restrict__ wte, float* __restrict__ x){
  int m = blockIdx.x, t = threadIdx.x;
  int token = tok[m];
  float4 f = ((const float4*)(wte + (size_t)token*1024))[t];
  ((float4*)(x + (size_t)m*1024))[t] = f;
}

// ---------------- LayerNorm: f32 in, bf16 out, one row per block -------------
__global__ __launch_bounds__(256) void ln_kernel(const float* __restrict__ x,
    const float* __restrict__ gam, const float* __restrict__ bet, u16* __restrict__ out){
  int m = blockIdx.x, t = threadIdx.x;
  float4 v = ((const float4*)(x + (size_t)m*1024))[t];
  float s  = v.x + v.y + v.z + v.w;
  float s2 = v.x*v.x + v.y*v.y + v.z*v.z + v.w*v.w;
  #pragma unroll
  for (int o = 32; o > 0; o >>= 1){ s += __shfl_xor(s, o); s2 += __shfl_xor(s2, o); }
  __shared__ float red[8];
  int w = t >> 6;
  if ((t & 63) == 0){ red[w] = s; red[4 + w] = s2; }
  __syncthreads();
  s  = red[0] + red[1] + red[2] + red[3];
  s2 = red[4] + red[5] + red[6] + red[7];
  float mean = s * (1.0f/1024.0f);
  float var  = s2 * (1.0f/1024.0f) - mean*mean;
  float inv  = rsqrtf(var + 1e-6f);
  float4 gv = ((const float4*)gam)[t];
  float4 bv = ((const float4*)bet)[t];
  u32 o0 = f2bf((v.x - mean)*inv*gv.x + bv.x);
  u32 o1 = f2bf((v.y - mean)*inv*gv.y + bv.y);
  u32 o2 = f2bf((v.z - mean)*inv*gv.z + bv.z);
  u32 o3 = f2bf((v.w - mean)*inv*gv.w + bv.w);
  uint2 ov; ov.x = o0 | (o1 << 16); ov.y = o2 | (o3 << 16);
  ((uint2*)(out + (size_t)m*1024))[t] = ov;
}

// ---------------- transpose core: 64x64 tile, src f32 or u16 -----------------
template<typename T>
DEVINL void transpose_tile(const T* __restrict__ src, u16* __restrict__ dst,
                           int ss, int ds, int c0, int r0, int t){
  __shared__ alignas(16) u16 tile[64][68];
  #pragma unroll
  for (int e = 0; e < 4; ++e){
    int idx = (e << 8) + t;
    int r = idx >> 4, c = (idx & 15) << 2;
    if constexpr (sizeof(T) == 4){
      float4 f = *(const float4*)(src + (size_t)(r0 + r)*ss + c0 + c);
      tile[r][c+0] = f2bf(f.x); tile[r][c+1] = f2bf(f.y);
      tile[r][c+2] = f2bf(f.z); tile[r][c+3] = f2bf(f.w);
    } else {
      uint2 u = *(const uint2*)(src + (size_t)(r0 + r)*ss + c0 + c);
      tile[r][c+0] = (u16)(u.x & 0xffffu); tile[r][c+1] = (u16)(u.x >> 16);
      tile[r][c+2] = (u16)(u.y & 0xffffu); tile[r][c+3] = (u16)(u.y >> 16);
    }
  }
  __syncthreads();
  #pragma unroll
  for (int e = 0; e < 4; ++e){
    int idx = (e << 8) + t;
    int cc = idx >> 4, rr = (idx & 15) << 2;
    uint2 u;
    u.x = (u32)tile[rr+0][cc] | ((u32)tile[rr+1][cc] << 16);
    u.y = (u32)tile[rr+2][cc] | ((u32)tile[rr+3][cc] << 16);
    *(uint2*)(dst + (size_t)(c0 + cc)*ds + r0 + rr) = u;
  }
}

template<typename T>
__global__ __launch_bounds__(256) void transpose_kernel(const T* __restrict__ src,
    u16* __restrict__ dst, int ss, int ds){
  transpose_tile<T>(src, dst, ss, ds, blockIdx.x << 6, blockIdx.y << 6, threadIdx.x);
}

// 3 square 1024x1024 f32 weights -> bf16 transposed, z selects the matrix
__global__ __launch_bounds__(256) void transpose3_kernel(const float* __restrict__ s0,
    const float* __restrict__ s1, const float* __restrict__ s2, u16* __restrict__ dst){
  const float* src = (blockIdx.z == 0) ? s0 : ((blockIdx.z == 1) ? s1 : s2);
  transpose_tile<float>(src, dst + (size_t)blockIdx.z*1048576, 1024, 1024,
                        blockIdx.x << 6, blockIdx.y << 6, threadIdx.x);
}

// ---------------- concat qkv biases for ALL layers -> b3[4][3072] ------------
__global__ __launch_bounds__(256) void concat_all_kernel(const float* __restrict__ bq,
    const float* __restrict__ bk, const float* __restrict__ bv, float* __restrict__ o){
  int g = blockIdx.x*256 + threadIdx.x;      // 0..12287
  int l = g / 3072, j = g % 3072;
  float v;
  if (j < 1024)      v = bq[l*1024 + j];
  else if (j < 2048) v = bk[l*1024 + j - 1024];
  else               v = bv[l*1024 + j - 2048];
  o[g] = v;
}

// ---------------- NT bf16 GEMM: C[m][n] = sum_k A[m][k]*B[n][k] ---------------
// BM x BN tile, BK=32, NWM x NWC waves (wave owns BM/NWM x BN/NWC), 16x16x32.
// bf16 path: 3-deep pipeline: 3 LDS buffers, STAGE(t+2) at t, counted
// s_waitcnt vmcnt(LW) + raw s_barrier. T2 swizzle: global source unit XOR
// ((lane>>3)&3), LDS dest linear, read unit qq ^ ((r>>1)&3).
// BF32 fallback (128/128/2/2 only): 2-buffer __syncthreads.
// XCD-chunked, m-inner block remap (B-panel reused (2048/BM)x from L2).
// mode 0: Cb=bf16(acc+bias); 1: Cb=bf16(gelu); 2: Cf+=acc+bias;
// mode 3: Cf=acc -- LDS-staged, 64B-aligned regular stores (no NT: round 9).
template<bool BF32, int BM, int BN, int NWM, int NWC>
__global__ __launch_bounds__(NWM*NWC*64) void gemm_nt(const u16* __restrict__ A,
    const void* __restrict__ Bp, const float* __restrict__ bias,
    u16* __restrict__ Cb, float* __restrict__ Cf,
    int N, int K, int mode){
  constexpr int NWAVES = NWM*NWC;
  constexpr int MI = BM / NWM / 16;           // per-wave m fragments
  constexpr int NI = BN / NWC / 16;           // per-wave n fragments
  constexpr int RPC = NWAVES*16;              // rows per stage line-call
  constexpr int ALC = BM / RPC;               // A line-calls per stage
  constexpr int BLC = BN / RPC;               // B line-calls per stage
  constexpr int LW  = ALC + BLC;              // loads in flight per stage
  constexpr int CHUNK = NWAVES*512;           // u16 per line-call
  constexpr int ASTR = BM*32;                 // u16 per A buffer
  constexpr int BSTR = BN*32;                 // u16 per B buffer
  constexpr int BUFSZ = ASTR + BSTR;
  constexpr int NBUF = BF32 ? 2 : 3;
  constexpr int MT  = 2048 / BM;              // m-tiles (gridDim.y)
  __shared__ alignas(16) u16 S[NBUF*BUFSZ];
  const int tid = threadIdx.x, lane = tid & 63, w = tid >> 6;
  const int wr = w / NWC, wc = w % NWC;
  // ---- XCD-chunked (bijective), m-inner remap ----
  const int nx = gridDim.x;
  const int nwg = nx * MT;
  const int flat = blockIdx.y * nx + blockIdx.x;
  const int qch = nwg >> 3, rch = nwg & 7;
  const int xcd = flat & 7, idxc = flat >> 3;
  const int nf = (xcd < rch ? xcd*(qch+1) : rch*(qch+1) + (xcd-rch)*qch) + idxc;
  const int m0 = (nf & (MT-1)) * BM;
  const int n0 = (nf / MT) * BN;
  const int r = lane & 15, qq = lane >> 4;
  const int srow = (w << 4) + (lane >> 2);    // staging row within a line-call
  const int sus  = lane & 3;                  // linear 16B unit within row
  const int su2  = sus ^ ((lane >> 3) & 3);   // swizzled global-source unit
  const int rsw  = (r >> 1) & 3;              // read-side swizzle term
  const f32x4 vzero = {0.f, 0.f, 0.f, 0.f};
  f32x4 acc[MI][NI];
  #pragma unroll
  for (int i = 0; i < MI; ++i)
    #pragma unroll
    for (int j = 0; j < NI; ++j) acc[i][j] = vzero;

  // staging source pointers at k=0
  const u16* pa[ALC];
  #pragma unroll
  for (int i = 0; i < ALC; ++i)
    pa[i] = A + (size_t)(m0 + i*RPC + srow)*K + (su2 << 3);
  const u16* pb[BLC > 0 ? BLC : 1];
  const float* pbf0 = nullptr; const float* pbf1 = nullptr;
  if constexpr (BF32){
    int nr0 = n0 + srow;      if (nr0 >= N) nr0 = N - 1;
    int nr1 = n0 + 64 + srow; if (nr1 >= N) nr1 = N - 1;
    pbf0 = (const float*)Bp + (size_t)nr0*K + (sus << 3);
    pbf1 = (const float*)Bp + (size_t)nr1*K + (sus << 3);
  } else {
    #pragma unroll
    for (int i = 0; i < BLC; ++i){
      int nr = n0 + i*RPC + srow; if (nr >= N) nr = N - 1;
      pb[i] = (const u16*)Bp + (size_t)nr*K + (su2 << 3);
    }
  }

  const int nkt = K >> 5;                      // >= 2 for all our shapes

#define GEMM_STAGE(dst, kofs) do {                                        \
    _Pragma("unroll")                                                     \
    for (int i = 0; i < ALC; ++i)                                         \
      gload16(pa[i] + (kofs), &(dst)[i*CHUNK + (w << 9)]);                \
    _Pragma("unroll")                                                     \
    for (int i = 0; i < BLC; ++i)                                         \
      gload16(pb[i] + (kofs), &(dst)[ASTR + i*CHUNK + (w << 9)]);         \
  } while(0)
#define GEMM_WAIT_LW() do {                                               \
    if constexpr (LW == 3) { WAITVM(3); }                                 \
    else if constexpr (LW == 4) { WAITVM(4); }                            \
    else { WAITVM(6); }                                                   \
  } while(0)
#define GEMM_COMPUTE(rdbuf) do {                                          \
    bf16x8 af[MI], bfv[NI];                                               \
    _Pragma("unroll")                                                     \
    for (int mi = 0; mi < MI; ++mi){                                      \
      int rowi = wr*(BM/NWM) + (mi << 4) + r;                             \
      af[mi] = *(const bf16x8*)&(rdbuf)[(rowi << 5) + ((qq ^ rsw) << 3)]; \
    }                                                                     \
    _Pragma("unroll")                                                     \
    for (int ni = 0; ni < NI; ++ni){                                      \
      int rowi = wc*(BN/NWC) + (ni << 4) + r;                             \
      bfv[ni] = *(const bf16x8*)&(rdbuf)[ASTR + (rowi << 5) + ((qq ^ rsw) << 3)]; \
    }                                                                     \
    _Pragma("unroll")                                                     \
    for (int mi = 0; mi < MI; ++mi)                                       \
      _Pragma("unroll")                                                   \
      for (int ni = 0; ni < NI; ++ni)                                     \
        acc[mi][ni] = __builtin_amdgcn_mfma_f32_16x16x32_bf16(af[mi], bfv[ni], acc[mi][ni], 0, 0, 0); \
  } while(0)

  if constexpr (!BF32){
    u16 *rd = S, *nxt = S + BUFSZ, *st = S + 2*BUFSZ;
    GEMM_STAGE(rd, 0);
    GEMM_STAGE(nxt, 32);
    GEMM_WAIT_LW();
    __builtin_amdgcn_sched_barrier(0);
    __builtin_amdgcn_s_barrier();
    __builtin_amdgcn_sched_barrier(0);
    for (int kt = 0; kt < nkt; ++kt){
      const bool more2 = (kt + 2 < nkt);
      if (more2){ GEMM_STAGE(st, (kt + 2) << 5); }
      GEMM_COMPUTE(rd);
      if (kt + 1 < nkt){
        if (more2){ GEMM_WAIT_LW(); } else { WAITVM(0); }
        __builtin_amdgcn_sched_barrier(0);
        __builtin_amdgcn_s_barrier();
        __builtin_amdgcn_sched_barrier(0);
        u16* t0 = rd; rd = nxt; nxt = st; st = t0;
      }
    }
  } else {
    // ---- BF32 fallback (128/128, 4 waves): 2-buffer, __syncthreads ----
    const int sw0 = (srow << 5) + (sus << 3);
    const int sw1 = ((srow + 64) << 5) + (sus << 3);
    {
      u16* Ab = S; u16* Bb = S + ASTR;
      #pragma unroll
      for (int i = 0; i < ALC; ++i) gload16(pa[i], &Ab[i*CHUNK + (w << 9)]);
      float4 g0 = *(const float4*)pbf0, g1 = *(const float4*)(pbf0 + 4);
      float4 g2 = *(const float4*)pbf1, g3 = *(const float4*)(pbf1 + 4);
      *(bf16x8*)&Bb[sw0] = cvt8(g0, g1);
      *(bf16x8*)&Bb[sw1] = cvt8(g2, g3);
      __syncthreads();
    }
    int buf = 0;
    for (int kt = 0; kt < nkt; ++kt){
      u16* Ab = S + buf*BUFSZ;
      u16* Bb = Ab + ASTR;
      const int nb = buf ^ 1;
      u16* An = S + nb*BUFSZ;
      u16* Bn = An + ASTR;
      float4 g0, g1, g2, g3;
      const bool more = (kt + 1 < nkt);
      if (more){
        const int k1 = (kt + 1) << 5;
        #pragma unroll
        for (int i = 0; i < ALC; ++i) gload16(pa[i] + k1, &An[i*CHUNK + (w << 9)]);
        g0 = *(const float4*)(pbf0 + k1); g1 = *(const float4*)(pbf0 + k1 + 4);
        g2 = *(const float4*)(pbf1 + k1); g3 = *(const float4*)(pbf1 + k1 + 4);
      }
      bf16x8 af[MI], bfv[NI];
      #pragma unroll
      for (int mi = 0; mi < MI; ++mi){
        int rowi = wr*(BM/NWM) + (mi << 4) + r;
        af[mi] = *(const bf16x8*)&Ab[(rowi << 5) + ((qq ^ rsw) << 3)];  // A swizzled
      }
      #pragma unroll
      for (int ni = 0; ni < NI; ++ni){
        int rowi = wc*(BN/NWC) + (ni << 4) + r;
        bfv[ni] = *(const bf16x8*)&Bb[(rowi << 5) + (qq << 3)];         // B linear
      }
      #pragma unroll
      for (int mi = 0; mi < MI; ++mi)
        #pragma unroll
        for (int ni = 0; ni < NI; ++ni)
          acc[mi][ni] = __builtin_amdgcn_mfma_f32_16x16x32_bf16(af[mi], bfv[ni], acc[mi][ni], 0, 0, 0);
      if (more){
        *(bf16x8*)&Bn[sw0] = cvt8(g0, g1);
        *(bf16x8*)&Bn[sw1] = cvt8(g2, g3);
      }
      __syncthreads();
      buf = nb;
    }
  }
#undef GEMM_STAGE
#undef GEMM_WAIT_LW
#undef GEMM_COMPUTE

  // ---- mode 3 (f32 store, no bias/act): LDS-staged, 64B-aligned stores ----
  if constexpr (BN == 128 && NWC == 2){
    if (mode == 3){
      float* ep = (float*)S;                 // 2 regions x 16 rows x 132 f32
      const int row16 = tid >> 3;            // 0..31
      const int wr2 = row16 >> 4, rr = row16 & 15;
      const int q8 = tid & 7;
      #pragma unroll
      for (int c = 0; c < MI; ++c){
        __syncthreads();
        #pragma unroll
        for (int ni = 0; ni < NI; ++ni)
          #pragma unroll
          for (int rg = 0; rg < 4; ++rg)
            ep[wr*2112 + ((qq << 2) + rg)*132 + wc*64 + (ni << 4) + r] = acc[c][ni][rg];
        __syncthreads();
        const float* src = &ep[wr2*2112 + rr*132];
        const int grow = m0 + wr2*(BM/2) + (c << 4) + rr;
        const size_t basef = (size_t)grow*N + n0;
        const int al = (int)((16 - (basef & 15)) & 15);
        if (q8 < 7){
          const int c0 = al + (q8 << 4);
          float* dst = &Cf[basef + c0];
          if (n0 + c0 + 15 < N){
            #pragma unroll
            for (int qk = 0; qk < 4; ++qk){
              f32x4 v;
              v[0] = src[c0 + qk*4 + 0]; v[1] = src[c0 + qk*4 + 1];
              v[2] = src[c0 + qk*4 + 2]; v[3] = src[c0 + qk*4 + 3];
              *(f32x4*)(dst + qk*4) = v;
            }
          } else {
            for (int i = 0; i < 16; ++i)
              if (n0 + c0 + i < N) dst[i] = src[c0 + i];
          }
        } else {
          for (int i = 0; i < al; ++i)
            if (n0 + i < N) Cf[basef + i] = src[i];
          for (int i = al + 112; i < 128; ++i)
            if (n0 + i < N) Cf[basef + i] = src[i];
        }
      }
      return;
    }
  }
  if constexpr (BN == 256 && NWC == 4){
    if (mode == 3){
      // 2 regions x 16 rows x 260 f32; 512 threads, 16 threads/row
      float* ep = (float*)S;
      const int row16 = tid >> 4;            // 0..31
      const int wr2 = row16 >> 4, rr = row16 & 15;
      const int q16 = tid & 15;
      #pragma unroll
      for (int c = 0; c < MI; ++c){
        __syncthreads();
        #pragma unroll
        for (int ni = 0; ni < NI; ++ni)
          #pragma unroll
          for (int rg = 0; rg < 4; ++rg)
            ep[wr*4160 + ((qq << 2) + rg)*260 + wc*64 + (ni << 4) + r] = acc[c][ni][rg];
        __syncthreads();
        const float* src = &ep[wr2*4160 + rr*260];
        const int grow = m0 + wr2*(BM/2) + (c << 4) + rr;
        const size_t basef = (size_t)grow*N + n0;
        const int al = (int)((16 - (basef & 15)) & 15);
        if (q16 < 15){
          const int c0 = al + (q16 << 4);
          float* dst = &Cf[basef + c0];
          if (n0 + c0 + 15 < N){
            #pragma unroll
            for (int qk = 0; qk < 4; ++qk){
              f32x4 v;
              v[0] = src[c0 + qk*4 + 0]; v[1] = src[c0 + qk*4 + 1];
              v[2] = src[c0 + qk*4 + 2]; v[3] = src[c0 + qk*4 + 3];
              *(f32x4*)(dst + qk*4) = v;
            }
          } else {
            for (int i = 0; i < 16; ++i)
              if (n0 + c0 + i < N) dst[i] = src[c0 + i];
          }
        } else {
          for (int i = 0; i < al; ++i)                 // ragged head
            if (n0 + i < N) Cf[basef + i] = src[i];
          for (int i = al + 240; i < 256; ++i)         // ragged tail
            if (n0 + i < N) Cf[basef + i] = src[i];
        }
      }
      return;
    }
  }

  // ---- generic epilogue (modes 0,1,2): C/D layout col=lane&15, row=(lane>>4)*4+reg
  #pragma unroll
  for (int ni = 0; ni < NI; ++ni){
    int col = n0 + wc*(BN/NWC) + (ni << 4) + r;
    if (col >= N) continue;
    float bb = bias ? bias[col] : 0.0f;
    #pragma unroll
    for (int mi = 0; mi < MI; ++mi){
      #pragma unroll
      for (int rg = 0; rg < 4; ++rg){
        int rowg = m0 + wr*(BM/NWM) + (mi << 4) + (qq << 2) + rg;
        float v = acc[mi][ni][rg] + bb;
        if (mode == 1){
          // gelu(tanh approx): v - v/(exp(1.5957691*(v+0.044715 v^3)) + 1)
          float z = 1.5957691216057308f * (v + 0.044715f*v*v*v);
          v = v - v / (__expf(z) + 1.0f);
        }
        if (mode == 2){
          Cf[(size_t)rowg*N + col] += v;
        } else {
          Cb[(size_t)rowg*N + col] = f2bf(v);
        }
      }
    }
  }
}

// ---------------- flash attention fwd ----------------------------------------
// One q-tile (64 rows) of one (b,h).
DEVINL void attn_tile(const u16* __restrict__ qkv, const u16* __restrict__ vt,
                      u16* __restrict__ o, int qt, int b, int h,
                      u16* Ks, u16* Vs, u16* Ps){
  const int tid = threadIdx.x, lane = tid & 63, w = tid >> 6;
  const int r = lane & 15, qq = lane >> 4;
  const int qrow0 = (qt << 6) + (w << 4);

  const u16* qp = qkv + (size_t)(b*1024 + qrow0 + r)*3072 + h*64 + (qq << 3);
  bf16x8 qf0 = *(const bf16x8*)qp;          // hd qq*8..+8
  bf16x8 qf1 = *(const bf16x8*)(qp + 32);   // hd 32+qq*8..+8

  const f32x4 vzero = {0.f, 0.f, 0.f, 0.f};
  float m_run[4], l_run[4];
  f32x4 acc_o[4];
  #pragma unroll
  for (int i = 0; i < 4; ++i){ m_run[i] = -1e30f; l_run[i] = 0.0f; acc_o[i] = vzero; }
  const float slope = exp2f(-0.5f*(float)(h + 1));   // ALiBi slopes for H=16

  for (int jt = 0; jt <= qt; ++jt){
    const int kv0 = jt << 6;
    __syncthreads();   // previous tile's K/V reads done
    #pragma unroll
    for (int e = 0; e < 2; ++e){
      int idx = (e << 8) + tid;
      int row = idx >> 3, ch = idx & 7;
      *(bf16x8*)&Ks[row*72 + (ch << 3)] =
        *(const bf16x8*)(qkv + (size_t)(b*1024 + kv0 + row)*3072 + 1024 + h*64 + (ch << 3));
      *(bf16x8*)&Vs[row*72 + (ch << 3)] =
        *(const bf16x8*)(vt + (size_t)(h*64 + row)*2048 + b*1024 + kv0 + (ch << 3));
    }
    __syncthreads();

    // S = Q K^T  (per wave: 16 q-rows x 64 kv)
    f32x4 sa[4];
    __builtin_amdgcn_s_setprio(1);
    #pragma unroll
    for (int ni = 0; ni < 4; ++ni){
      f32x4 z = vzero;
      bf16x8 kf0 = *(const bf16x8*)&Ks[(ni*16 + r)*72 + (qq << 3)];
      bf16x8 kf1 = *(const bf16x8*)&Ks[(ni*16 + r)*72 + 32 + (qq << 3)];
      z = __builtin_amdgcn_mfma_f32_16x16x32_bf16(qf0, kf0, z, 0, 0, 0);
      z = __builtin_amdgcn_mfma_f32_16x16x32_bf16(qf1, kf1, z, 0, 0, 0);
      sa[ni] = z;
    }
    __builtin_amdgcn_s_setprio(0);
    // scale + alibi (col-only) + clamp + causal mask
    float mx[4] = {-1e30f, -1e30f, -1e30f, -1e30f};
    #pragma unroll
    for (int ni = 0; ni < 4; ++ni){
      int colg = kv0 + ni*16 + r;
      float ab = -slope * (float)(1023 - colg);
      #pragma unroll
      for (int rg = 0; rg < 4; ++rg){
        int rowg = (qt << 6) + (w << 4) + (qq << 2) + rg;
        float sv = sa[ni][rg]*0.125f + ab;
        sv = fminf(sv, 60.0f);             // NaN firewall; legit scores << 60
        sv = (colg > rowg) ? -1e30f : sv;
        sa[ni][rg] = sv;
        mx[rg] = fmaxf(mx[rg], sv);
      }
    }
    #pragma unroll
    for (int off = 1; off < 16; off <<= 1){
      #pragma unroll
      for (int rg = 0; rg < 4; ++rg) mx[rg] = fmaxf(mx[rg], __shfl_xor(mx[rg], off));
    }
    float alpha[4], rs[4];
    #pragma unroll
    for (int rg = 0; rg < 4; ++rg){
      float mn = fmaxf(m_run[rg], mx[rg]);
      alpha[rg] = __expf(m_run[rg] - mn);
      m_run[rg] = mn;
      rs[rg] = 0.0f;
    }
    u16* pw = Ps;
    #pragma unroll
    for (int ni = 0; ni < 4; ++ni){
      #pragma unroll
      for (int rg = 0; rg < 4; ++rg){
        float p = __expf(sa[ni][rg] - m_run[rg]);
        rs[rg] += p;
        pw[(qq*4 + rg)*72 + ni*16 + r] = f2bf(p);   // P[qrow][kv], wave-local
      }
    }
    #pragma unroll
    for (int off = 1; off < 16; off <<= 1){
      #pragma unroll
      for (int rg = 0; rg < 4; ++rg) rs[rg] += __shfl_xor(rs[rg], off);
    }
    #pragma unroll
    for (int rg = 0; rg < 4; ++rg) l_run[rg] = l_run[rg]*alpha[rg] + rs[rg];
    #pragma unroll
    for (int ni = 0; ni < 4; ++ni)
      #pragma unroll
      for (int rg = 0; rg < 4; ++rg) acc_o[ni][rg] *= alpha[rg];
    __syncthreads();   // P stores visible before vector reload (ordering guard)
    // O += P V   (A = P from LDS, B = V^T rows -> k-contiguous)
    __builtin_amdgcn_s_setprio(1);
    #pragma unroll
    for (int kk = 0; kk < 2; ++kk){
      bf16x8 pa = *(const bf16x8*)&pw[r*72 + (kk << 5) + (qq << 3)];
      #pragma unroll
      for (int ni = 0; ni < 4; ++ni){
        bf16x8 vf = *(const bf16x8*)&Vs[(ni*16 + r)*72 + (kk << 5) + (qq << 3)];
        acc_o[ni] = __builtin_amdgcn_mfma_f32_16x16x32_bf16(pa, vf, acc_o[ni], 0, 0, 0);
      }
    }
    __builtin_amdgcn_s_setprio(0);
  }
  #pragma unroll
  for (int ni = 0; ni < 4; ++ni){
    #pragma unroll
    for (int rg = 0; rg < 4; ++rg){
      int rowg = b*1024 + (qt << 6) + (w << 4) + (qq << 2) + rg;
      o[(size_t)rowg*1024 + h*64 + ni*16 + r] = f2bf(acc_o[ni][rg] / l_run[rg]);
    }
  }
}

// grid (16,32) = 512 blocks, 2/CU co-resident. Complementary pairing: blocks
// c and c+256 (which share a CU per round-16 evidence) get q-tiles p and 15-p
// of the same bh set -> every CU totals 17 KV-tile-units at 8 waves/CU.
__global__ __launch_bounds__(256) void attn_kernel(const u16* __restrict__ qkv,
    const u16* __restrict__ vt, u16* __restrict__ o){
  const int flat = blockIdx.y * 16 + blockIdx.x;   // 0..511
  const int hi = flat >> 8;                        // 0 or 1
  const int i  = flat & 255;
  const int bh = i & 31;
  const int p  = i >> 5;                           // 0..7
  const int qt = hi ? (15 - p) : p;
  const int b = bh >> 4, h = bh & 15;
  const int w = threadIdx.x >> 6;
  __shared__ alignas(16) u16 Ks[64*72];     // K tile [kv][hd], pad 8
  __shared__ alignas(16) u16 Vs[64*72];     // V^T tile [hd][kv], pad 8
  __shared__ alignas(16) u16 Ps[4][16*72];  // per-wave P [qrow][kv]
  attn_tile(qkv, vt, o, qt, b, h, Ks, Vs, &Ps[w][0]);
}

// ---------------- driver ------------------------------------------------------
extern "C" void kernel_launch(void* const* d_in, const int* in_sizes, int n_in,
                              void* d_out, int out_size, void* d_ws, size_t ws_size,
                              hipStream_t stream){
  (void)in_sizes; (void)n_in; (void)out_size;
  const int*   tok  = (const int*)d_in[0];
  const float* wte  = (const float*)d_in[1];
  const float* ln1s = (const float*)d_in[2];
  const float* ln1b = (const float*)d_in[3];
  const float* Wq   = (const float*)d_in[4];
  const float* bq   = (const float*)d_in[5];
  const float* Wk   = (const float*)d_in[6];
  const float* bk   = (const float*)d_in[7];
  const float* Wv   = (const float*)d_in[8];
  const float* bv   = (const float*)d_in[9];
  const float* Wo   = (const float*)d_in[10];
  const float* bo   = (const float*)d_in[11];
  const float* ln2s = (const float*)d_in[12];
  const float* ln2b = (const float*)d_in[13];
  const float* Wfi  = (const float*)d_in[14];
  const float* bfi  = (const float*)d_in[15];
  const float* Wfo  = (const float*)d_in[16];
  const float* bfo  = (const float*)d_in[17];
  const float* lnfs = (const float*)d_in[18];
  const float* lnfb = (const float*)d_in[19];

  char* ws = (char*)d_ws;
  float* x   = (float*)(ws);
  u16* h     = (u16*)(ws + ( 8u << 20));
  u16* qkv   = (u16*)(ws + (12u << 20));
  u16* v_t   = (u16*)(ws + (24u << 20));
  u16* attnb = (u16*)(ws + (28u << 20));
  u16* ffn   = (u16*)(ws + (32u << 20));
  u16* wT    = (u16*)(ws + (48u << 20));
  float* b3  = (float*)(ws + (56u << 20));
  u16* wteb  = (u16*)(ws + (57u << 20));

  const size_t wteb_bytes = (size_t)50257 * 1024 * 2;
  const bool big_ws = ws_size >= ((size_t)(57u) << 20) + wteb_bytes;

  if (big_ws){
    // convert wte to bf16 once (51,463,168 elems = 6,432,896 lanes of 8)
    cvt_bf16_kernel<<<25129, 256, 0, stream>>>(wte, wteb, 6432896);
  }
  embed_kernel<<<2048, 256, 0, stream>>>(tok, wte, x);
  concat_all_kernel<<<48, 256, 0, stream>>>(bq, bk, bv, b3);
  for (int i = 0; i < 4; ++i){
    ln_kernel<<<2048, 256, 0, stream>>>(x, ln1s + i*1024, ln1b + i*1024, h);
    transpose3_kernel<<<dim3(16,16,3), 256, 0, stream>>>(
        Wq + (size_t)i*1048576, Wk + (size_t)i*1048576, Wv + (size_t)i*1048576, wT);
    gemm_nt<false,64,128,2,2><<<dim3(24,32), 256, 0, stream>>>(h, wT, b3 + i*3072, qkv, nullptr, 3072, 1024, 0);
    transpose_kernel<u16><<<dim3(16,32), 256, 0, stream>>>(qkv + 2048, v_t, 3072, 2048);
    attn_kernel<<<dim3(16,32), 256, 0, stream>>>(qkv, v_t, attnb);
    transpose_kernel<float><<<dim3(16,16), 256, 0, stream>>>(Wo + (size_t)i*1048576, wT, 1024, 1024);
    gemm_nt<false,128,64,2,2><<<dim3(16,16), 256, 0, stream>>>(attnb, wT, bo + i*1024, nullptr, x, 1024, 1024, 2);
    ln_kernel<<<2048, 256, 0, stream>>>(x, ln2s + i*1024, ln2b + i*1024, h);
    transpose_kernel<float><<<dim3(64,16), 256, 0, stream>>>(Wfi + (size_t)i*4194304, wT, 4096, 1024);
    gemm_nt<false,128,256,2,4><<<dim3(16,16), 512, 0, stream>>>(h, wT, bfi + i*4096, ffn, nullptr, 4096, 1024, 1);
    transpose_kernel<float><<<dim3(16,64), 256, 0, stream>>>(Wfo + (size_t)i*4194304, wT, 1024, 4096);
    gemm_nt<false,128,64,2,2><<<dim3(16,16), 256, 0, stream>>>(ffn, wT, bfo + i*1024, nullptr, x, 1024, 4096, 2);
  }
  ln_kernel<<<2048, 256, 0, stream>>>(x, lnfs, lnfb, h);
  if (big_ws){
    gemm_nt<false,128,256,2,4><<<dim3(197,16), 512, 0, stream>>>(h, wteb, nullptr, nullptr, (float*)d_out, 50257, 1024, 3);
  } else {
    gemm_nt<true,128,128,2,2><<<dim3(393,16), 256, 0, stream>>>(h, wte, nullptr, nullptr, (float*)d_out, 50257, 1024, 3);
  }
}

// Round 19
// 1111.263 us; speedup vs baseline: 1.0404x; 1.0404x over previous
//
#include <hip/hip_runtime.h>
#include <hip/hip_bf16.h>

// Transformer forward, MI355X gfx950.
// Inputs/outputs are FLOAT32 (per reference). bf16 is used only as the MFMA
// compute format; residual stream, LN, softmax, biases, logits all f32.
// Workspace layout (bytes):
//   x     f32 [2048][1024]   @ 0      (8 MB)   residual stream
//   h     bf16[2048][1024]   @ 8 MB   (4 MB)   LN outputs
//   qkv   bf16[2048][3072]   @ 12 MB  (12 MB)
//   v_t   bf16[1024][2048]   @ 24 MB  (4 MB)   V transposed for attention
//   attn  bf16[2048][1024]   @ 28 MB  (4 MB)
//   ffn   bf16[2048][4096]   @ 32 MB  (16 MB)
//   wT    bf16 (<=8 MB)      @ 48 MB  (8 MB)   transposed+converted weights
//   b3    f32 [4][3072]      @ 56 MB  (48 KB)  all-layer qkv bias
//   wteb  bf16[50257][1024]  @ 57 MB  (103 MB) bf16 copy of wte (if ws fits)
//
// Round 11/12: per-WAVE acc must stay <= 64 regs (8-wave fat tiles).
// Round 16/17: co-resident blocks c and c+256 share a CU -> attention uses
// COMPLEMENTARY qt pairing (p with 15-p) => 17 tile-units per CU, 8 waves/CU.
// Round 18 lesson: BM=64 is neutral where CUs already had >=8 waves (qkv);
// Round 19: apply BM=64 where ALL CUs were at 4 waves (attn-out, ffn2:
// 256 blocks = 1 block/CU) -> 512 blocks = 2/CU = 8 waves/CU.

typedef unsigned short u16;
typedef unsigned int u32;
typedef __attribute__((ext_vector_type(8))) short bf16x8;   // 8 bf16 = 4 VGPR
typedef __attribute__((ext_vector_type(4))) float f32x4;

#define DEVINL static __device__ __forceinline__
#define WAITVM(N) asm volatile("s_waitcnt vmcnt(" #N ")" ::: "memory")

DEVINL u16 f2bf(float f){ __hip_bfloat16 h = __float2bfloat16(f); return *reinterpret_cast<u16*>(&h); }

DEVINL bf16x8 cvt8(float4 a, float4 b){
  bf16x8 r;
  r[0] = (short)f2bf(a.x); r[1] = (short)f2bf(a.y);
  r[2] = (short)f2bf(a.z); r[3] = (short)f2bf(a.w);
  r[4] = (short)f2bf(b.x); r[5] = (short)f2bf(b.y);
  r[6] = (short)f2bf(b.z); r[7] = (short)f2bf(b.w);
  return r;
}

DEVINL void gload16(const u16* g, u16* l){
  // async global->LDS: per-lane GLOBAL source, wave-uniform LDS base + lane*16
  __builtin_amdgcn_global_load_lds((const __attribute__((address_space(1))) void*)g,
                                   (__attribute__((address_space(3))) void*)l, 16, 0, 0);
}

// ---------------- f32 -> bf16 bulk convert (8 elems/lane) --------------------
__global__ __launch_bounds__(256) void cvt_bf16_kernel(const float* __restrict__ src,
    u16* __restrict__ dst, int n8){
  int i = blockIdx.x*256 + threadIdx.x;
  if (i >= n8) return;
  const float4* p = (const float4*)(src + (size_t)i*8);
  float4 a = p[0], b = p[1];
  *(bf16x8*)(dst + (size_t)i*8) = cvt8(a, b);
}

// ---------------- embedding gather: x[m][:] = wte[tok[m]][:] (f32 copy) ------
__global__ __launch_bounds__(256) void embed_kernel(const int* __restrict__ tok,
    const float* __restrict__ wte, float* __restrict__ x){
  int m = blockIdx.x, t = threadIdx.x;
  int token = tok[m];
  float4 f = ((const float4*)(wte + (size_t)token*1024))[t];
  ((float4*)(x + (size_t)m*1024))[t] = f;
}

// ---------------- LayerNorm: f32 in, bf16 out, one row per block -------------
__global__ __launch_bounds__(256) void ln_kernel(const float* __restrict__ x,
    const float* __restrict__ gam, const float* __restrict__ bet, u16* __restrict__ out){
  int m = blockIdx.x, t = threadIdx.x;
  float4 v = ((const float4*)(x + (size_t)m*1024))[t];
  float s  = v.x + v.y + v.z + v.w;
  float s2 = v.x*v.x + v.y*v.y + v.z*v.z + v.w*v.w;
  #pragma unroll
  for (int o = 32; o > 0; o >>= 1){ s += __shfl_xor(s, o); s2 += __shfl_xor(s2, o); }
  __shared__ float red[8];
  int w = t >> 6;
  if ((t & 63) == 0){ red[w] = s; red[4 + w] = s2; }
  __syncthreads();
  s  = red[0] + red[1] + red[2] + red[3];
  s2 = red[4] + red[5] + red[6] + red[7];
  float mean = s * (1.0f/1024.0f);
  float var  = s2 * (1.0f/1024.0f) - mean*mean;
  float inv  = rsqrtf(var + 1e-6f);
  float4 gv = ((const float4*)gam)[t];
  float4 bv = ((const float4*)bet)[t];
  u32 o0 = f2bf((v.x - mean)*inv*gv.x + bv.x);
  u32 o1 = f2bf((v.y - mean)*inv*gv.y + bv.y);
  u32 o2 = f2bf((v.z - mean)*inv*gv.z + bv.z);
  u32 o3 = f2bf((v.w - mean)*inv*gv.w + bv.w);
  uint2 ov; ov.x = o0 | (o1 << 16); ov.y = o2 | (o3 << 16);
  ((uint2*)(out + (size_t)m*1024))[t] = ov;
}

// ---------------- transpose core: 64x64 tile, src f32 or u16 -----------------
template<typename T>
DEVINL void transpose_tile(const T* __restrict__ src, u16* __restrict__ dst,
                           int ss, int ds, int c0, int r0, int t){
  __shared__ alignas(16) u16 tile[64][68];
  #pragma unroll
  for (int e = 0; e < 4; ++e){
    int idx = (e << 8) + t;
    int r = idx >> 4, c = (idx & 15) << 2;
    if constexpr (sizeof(T) == 4){
      float4 f = *(const float4*)(src + (size_t)(r0 + r)*ss + c0 + c);
      tile[r][c+0] = f2bf(f.x); tile[r][c+1] = f2bf(f.y);
      tile[r][c+2] = f2bf(f.z); tile[r][c+3] = f2bf(f.w);
    } else {
      uint2 u = *(const uint2*)(src + (size_t)(r0 + r)*ss + c0 + c);
      tile[r][c+0] = (u16)(u.x & 0xffffu); tile[r][c+1] = (u16)(u.x >> 16);
      tile[r][c+2] = (u16)(u.y & 0xffffu); tile[r][c+3] = (u16)(u.y >> 16);
    }
  }
  __syncthreads();
  #pragma unroll
  for (int e = 0; e < 4; ++e){
    int idx = (e << 8) + t;
    int cc = idx >> 4, rr = (idx & 15) << 2;
    uint2 u;
    u.x = (u32)tile[rr+0][cc] | ((u32)tile[rr+1][cc] << 16);
    u.y = (u32)tile[rr+2][cc] | ((u32)tile[rr+3][cc] << 16);
    *(uint2*)(dst + (size_t)(c0 + cc)*ds + r0 + rr) = u;
  }
}

template<typename T>
__global__ __launch_bounds__(256) void transpose_kernel(const T* __restrict__ src,
    u16* __restrict__ dst, int ss, int ds){
  transpose_tile<T>(src, dst, ss, ds, blockIdx.x << 6, blockIdx.y << 6, threadIdx.x);
}

// 3 square 1024x1024 f32 weights -> bf16 transposed, z selects the matrix
__global__ __launch_bounds__(256) void transpose3_kernel(const float* __restrict__ s0,
    const float* __restrict__ s1, const float* __restrict__ s2, u16* __restrict__ dst){
  const float* src = (blockIdx.z == 0) ? s0 : ((blockIdx.z == 1) ? s1 : s2);
  transpose_tile<float>(src, dst + (size_t)blockIdx.z*1048576, 1024, 1024,
                        blockIdx.x << 6, blockIdx.y << 6, threadIdx.x);
}

// ---------------- concat qkv biases for ALL layers -> b3[4][3072] ------------
__global__ __launch_bounds__(256) void concat_all_kernel(const float* __restrict__ bq,
    const float* __restrict__ bk, const float* __restrict__ bv, float* __restrict__ o){
  int g = blockIdx.x*256 + threadIdx.x;      // 0..12287
  int l = g / 3072, j = g % 3072;
  float v;
  if (j < 1024)      v = bq[l*1024 + j];
  else if (j < 2048) v = bk[l*1024 + j - 1024];
  else               v = bv[l*1024 + j - 2048];
  o[g] = v;
}

// ---------------- NT bf16 GEMM: C[m][n] = sum_k A[m][k]*B[n][k] ---------------
// BM x BN tile, BK=32, NWM x NWC waves (wave owns BM/NWM x BN/NWC), 16x16x32.
// bf16 path: 3-deep pipeline: 3 LDS buffers, STAGE(t+2) at t, counted
// s_waitcnt vmcnt(LW) + raw s_barrier. T2 swizzle: global source unit XOR
// ((lane>>3)&3), LDS dest linear, read unit qq ^ ((r>>1)&3).
// BF32 fallback (128/128/2/2 only): 2-buffer __syncthreads.
// XCD-chunked, m-inner block remap (B-panel reused (2048/BM)x from L2).
// mode 0: Cb=bf16(acc+bias); 1: Cb=bf16(gelu); 2: Cf+=acc+bias;
// mode 3: Cf=acc -- LDS-staged, 64B-aligned regular stores (no NT: round 9).
template<bool BF32, int BM, int BN, int NWM, int NWC>
__global__ __launch_bounds__(NWM*NWC*64) void gemm_nt(const u16* __restrict__ A,
    const void* __restrict__ Bp, const float* __restrict__ bias,
    u16* __restrict__ Cb, float* __restrict__ Cf,
    int N, int K, int mode){
  constexpr int NWAVES = NWM*NWC;
  constexpr int MI = BM / NWM / 16;           // per-wave m fragments
  constexpr int NI = BN / NWC / 16;           // per-wave n fragments
  constexpr int RPC = NWAVES*16;              // rows per stage line-call
  constexpr int ALC = BM / RPC;               // A line-calls per stage
  constexpr int BLC = BN / RPC;               // B line-calls per stage
  constexpr int LW  = ALC + BLC;              // loads in flight per stage
  constexpr int CHUNK = NWAVES*512;           // u16 per line-call
  constexpr int ASTR = BM*32;                 // u16 per A buffer
  constexpr int BSTR = BN*32;                 // u16 per B buffer
  constexpr int BUFSZ = ASTR + BSTR;
  constexpr int NBUF = BF32 ? 2 : 3;
  constexpr int MT  = 2048 / BM;              // m-tiles (gridDim.y)
  __shared__ alignas(16) u16 S[NBUF*BUFSZ];
  const int tid = threadIdx.x, lane = tid & 63, w = tid >> 6;
  const int wr = w / NWC, wc = w % NWC;
  // ---- XCD-chunked (bijective), m-inner remap ----
  const int nx = gridDim.x;
  const int nwg = nx * MT;
  const int flat = blockIdx.y * nx + blockIdx.x;
  const int qch = nwg >> 3, rch = nwg & 7;
  const int xcd = flat & 7, idxc = flat >> 3;
  const int nf = (xcd < rch ? xcd*(qch+1) : rch*(qch+1) + (xcd-rch)*qch) + idxc;
  const int m0 = (nf & (MT-1)) * BM;
  const int n0 = (nf / MT) * BN;
  const int r = lane & 15, qq = lane >> 4;
  const int srow = (w << 4) + (lane >> 2);    // staging row within a line-call
  const int sus  = lane & 3;                  // linear 16B unit within row
  const int su2  = sus ^ ((lane >> 3) & 3);   // swizzled global-source unit
  const int rsw  = (r >> 1) & 3;              // read-side swizzle term
  const f32x4 vzero = {0.f, 0.f, 0.f, 0.f};
  f32x4 acc[MI][NI];
  #pragma unroll
  for (int i = 0; i < MI; ++i)
    #pragma unroll
    for (int j = 0; j < NI; ++j) acc[i][j] = vzero;

  // staging source pointers at k=0
  const u16* pa[ALC];
  #pragma unroll
  for (int i = 0; i < ALC; ++i)
    pa[i] = A + (size_t)(m0 + i*RPC + srow)*K + (su2 << 3);
  const u16* pb[BLC > 0 ? BLC : 1];
  const float* pbf0 = nullptr; const float* pbf1 = nullptr;
  if constexpr (BF32){
    int nr0 = n0 + srow;      if (nr0 >= N) nr0 = N - 1;
    int nr1 = n0 + 64 + srow; if (nr1 >= N) nr1 = N - 1;
    pbf0 = (const float*)Bp + (size_t)nr0*K + (sus << 3);
    pbf1 = (const float*)Bp + (size_t)nr1*K + (sus << 3);
  } else {
    #pragma unroll
    for (int i = 0; i < BLC; ++i){
      int nr = n0 + i*RPC + srow; if (nr >= N) nr = N - 1;
      pb[i] = (const u16*)Bp + (size_t)nr*K + (su2 << 3);
    }
  }

  const int nkt = K >> 5;                      // >= 2 for all our shapes

#define GEMM_STAGE(dst, kofs) do {                                        \
    _Pragma("unroll")                                                     \
    for (int i = 0; i < ALC; ++i)                                         \
      gload16(pa[i] + (kofs), &(dst)[i*CHUNK + (w << 9)]);                \
    _Pragma("unroll")                                                     \
    for (int i = 0; i < BLC; ++i)                                         \
      gload16(pb[i] + (kofs), &(dst)[ASTR + i*CHUNK + (w << 9)]);         \
  } while(0)
#define GEMM_WAIT_LW() do {                                               \
    if constexpr (LW == 2) { WAITVM(2); }                                 \
    else if constexpr (LW == 3) { WAITVM(3); }                            \
    else if constexpr (LW == 4) { WAITVM(4); }                            \
    else { WAITVM(6); }                                                   \
  } while(0)
#define GEMM_COMPUTE(rdbuf) do {                                          \
    bf16x8 af[MI], bfv[NI];                                               \
    _Pragma("unroll")                                                     \
    for (int mi = 0; mi < MI; ++mi){                                      \
      int rowi = wr*(BM/NWM) + (mi << 4) + r;                             \
      af[mi] = *(const bf16x8*)&(rdbuf)[(rowi << 5) + ((qq ^ rsw) << 3)]; \
    }                                                                     \
    _Pragma("unroll")                                                     \
    for (int ni = 0; ni < NI; ++ni){                                      \
      int rowi = wc*(BN/NWC) + (ni << 4) + r;                             \
      bfv[ni] = *(const bf16x8*)&(rdbuf)[ASTR + (rowi << 5) + ((qq ^ rsw) << 3)]; \
    }                                                                     \
    _Pragma("unroll")                                                     \
    for (int mi = 0; mi < MI; ++mi)                                       \
      _Pragma("unroll")                                                   \
      for (int ni = 0; ni < NI; ++ni)                                     \
        acc[mi][ni] = __builtin_amdgcn_mfma_f32_16x16x32_bf16(af[mi], bfv[ni], acc[mi][ni], 0, 0, 0); \
  } while(0)

  if constexpr (!BF32){
    u16 *rd = S, *nxt = S + BUFSZ, *st = S + 2*BUFSZ;
    GEMM_STAGE(rd, 0);
    GEMM_STAGE(nxt, 32);
    GEMM_WAIT_LW();
    __builtin_amdgcn_sched_barrier(0);
    __builtin_amdgcn_s_barrier();
    __builtin_amdgcn_sched_barrier(0);
    for (int kt = 0; kt < nkt; ++kt){
      const bool more2 = (kt + 2 < nkt);
      if (more2){ GEMM_STAGE(st, (kt + 2) << 5); }
      GEMM_COMPUTE(rd);
      if (kt + 1 < nkt){
        if (more2){ GEMM_WAIT_LW(); } else { WAITVM(0); }
        __builtin_amdgcn_sched_barrier(0);
        __builtin_amdgcn_s_barrier();
        __builtin_amdgcn_sched_barrier(0);
        u16* t0 = rd; rd = nxt; nxt = st; st = t0;
      }
    }
  } else {
    // ---- BF32 fallback (128/128, 4 waves): 2-buffer, __syncthreads ----
    const int sw0 = (srow << 5) + (sus << 3);
    const int sw1 = ((srow + 64) << 5) + (sus << 3);
    {
      u16* Ab = S; u16* Bb = S + ASTR;
      #pragma unroll
      for (int i = 0; i < ALC; ++i) gload16(pa[i], &Ab[i*CHUNK + (w << 9)]);
      float4 g0 = *(const float4*)pbf0, g1 = *(const float4*)(pbf0 + 4);
      float4 g2 = *(const float4*)pbf1, g3 = *(const float4*)(pbf1 + 4);
      *(bf16x8*)&Bb[sw0] = cvt8(g0, g1);
      *(bf16x8*)&Bb[sw1] = cvt8(g2, g3);
      __syncthreads();
    }
    int buf = 0;
    for (int kt = 0; kt < nkt; ++kt){
      u16* Ab = S + buf*BUFSZ;
      u16* Bb = Ab + ASTR;
      const int nb = buf ^ 1;
      u16* An = S + nb*BUFSZ;
      u16* Bn = An + ASTR;
      float4 g0, g1, g2, g3;
      const bool more = (kt + 1 < nkt);
      if (more){
        const int k1 = (kt + 1) << 5;
        #pragma unroll
        for (int i = 0; i < ALC; ++i) gload16(pa[i] + k1, &An[i*CHUNK + (w << 9)]);
        g0 = *(const float4*)(pbf0 + k1); g1 = *(const float4*)(pbf0 + k1 + 4);
        g2 = *(const float4*)(pbf1 + k1); g3 = *(const float4*)(pbf1 + k1 + 4);
      }
      bf16x8 af[MI], bfv[NI];
      #pragma unroll
      for (int mi = 0; mi < MI; ++mi){
        int rowi = wr*(BM/NWM) + (mi << 4) + r;
        af[mi] = *(const bf16x8*)&Ab[(rowi << 5) + ((qq ^ rsw) << 3)];  // A swizzled
      }
      #pragma unroll
      for (int ni = 0; ni < NI; ++ni){
        int rowi = wc*(BN/NWC) + (ni << 4) + r;
        bfv[ni] = *(const bf16x8*)&Bb[(rowi << 5) + (qq << 3)];         // B linear
      }
      #pragma unroll
      for (int mi = 0; mi < MI; ++mi)
        #pragma unroll
        for (int ni = 0; ni < NI; ++ni)
          acc[mi][ni] = __builtin_amdgcn_mfma_f32_16x16x32_bf16(af[mi], bfv[ni], acc[mi][ni], 0, 0, 0);
      if (more){
        *(bf16x8*)&Bn[sw0] = cvt8(g0, g1);
        *(bf16x8*)&Bn[sw1] = cvt8(g2, g3);
      }
      __syncthreads();
      buf = nb;
    }
  }
#undef GEMM_STAGE
#undef GEMM_WAIT_LW
#undef GEMM_COMPUTE

  // ---- mode 3 (f32 store, no bias/act): LDS-staged, 64B-aligned stores ----
  if constexpr (BN == 128 && NWC == 2){
    if (mode == 3){
      float* ep = (float*)S;                 // 2 regions x 16 rows x 132 f32
      const int row16 = tid >> 3;            // 0..31
      const int wr2 = row16 >> 4, rr = row16 & 15;
      const int q8 = tid & 7;
      #pragma unroll
      for (int c = 0; c < MI; ++c){
        __syncthreads();
        #pragma unroll
        for (int ni = 0; ni < NI; ++ni)
          #pragma unroll
          for (int rg = 0; rg < 4; ++rg)
            ep[wr*2112 + ((qq << 2) + rg)*132 + wc*64 + (ni << 4) + r] = acc[c][ni][rg];
        __syncthreads();
        const float* src = &ep[wr2*2112 + rr*132];
        const int grow = m0 + wr2*(BM/2) + (c << 4) + rr;
        const size_t basef = (size_t)grow*N + n0;
        const int al = (int)((16 - (basef & 15)) & 15);
        if (q8 < 7){
          const int c0 = al + (q8 << 4);
          float* dst = &Cf[basef + c0];
          if (n0 + c0 + 15 < N){
            #pragma unroll
            for (int qk = 0; qk < 4; ++qk){
              f32x4 v;
              v[0] = src[c0 + qk*4 + 0]; v[1] = src[c0 + qk*4 + 1];
              v[2] = src[c0 + qk*4 + 2]; v[3] = src[c0 + qk*4 + 3];
              *(f32x4*)(dst + qk*4) = v;
            }
          } else {
            for (int i = 0; i < 16; ++i)
              if (n0 + c0 + i < N) dst[i] = src[c0 + i];
          }
        } else {
          for (int i = 0; i < al; ++i)
            if (n0 + i < N) Cf[basef + i] = src[i];
          for (int i = al + 112; i < 128; ++i)
            if (n0 + i < N) Cf[basef + i] = src[i];
        }
      }
      return;
    }
  }
  if constexpr (BN == 256 && NWC == 4){
    if (mode == 3){
      // 2 regions x 16 rows x 260 f32; 512 threads, 16 threads/row
      float* ep = (float*)S;
      const int row16 = tid >> 4;            // 0..31
      const int wr2 = row16 >> 4, rr = row16 & 15;
      const int q16 = tid & 15;
      #pragma unroll
      for (int c = 0; c < MI; ++c){
        __syncthreads();
        #pragma unroll
        for (int ni = 0; ni < NI; ++ni)
          #pragma unroll
          for (int rg = 0; rg < 4; ++rg)
            ep[wr*4160 + ((qq << 2) + rg)*260 + wc*64 + (ni << 4) + r] = acc[c][ni][rg];
        __syncthreads();
        const float* src = &ep[wr2*4160 + rr*260];
        const int grow = m0 + wr2*(BM/2) + (c << 4) + rr;
        const size_t basef = (size_t)grow*N + n0;
        const int al = (int)((16 - (basef & 15)) & 15);
        if (q16 < 15){
          const int c0 = al + (q16 << 4);
          float* dst = &Cf[basef + c0];
          if (n0 + c0 + 15 < N){
            #pragma unroll
            for (int qk = 0; qk < 4; ++qk){
              f32x4 v;
              v[0] = src[c0 + qk*4 + 0]; v[1] = src[c0 + qk*4 + 1];
              v[2] = src[c0 + qk*4 + 2]; v[3] = src[c0 + qk*4 + 3];
              *(f32x4*)(dst + qk*4) = v;
            }
          } else {
            for (int i = 0; i < 16; ++i)
              if (n0 + c0 + i < N) dst[i] = src[c0 + i];
          }
        } else {
          for (int i = 0; i < al; ++i)                 // ragged head
            if (n0 + i < N) Cf[basef + i] = src[i];
          for (int i = al + 240; i < 256; ++i)         // ragged tail
            if (n0 + i < N) Cf[basef + i] = src[i];
        }
      }
      return;
    }
  }

  // ---- generic epilogue (modes 0,1,2): C/D layout col=lane&15, row=(lane>>4)*4+reg
  #pragma unroll
  for (int ni = 0; ni < NI; ++ni){
    int col = n0 + wc*(BN/NWC) + (ni << 4) + r;
    if (col >= N) continue;
    float bb = bias ? bias[col] : 0.0f;
    #pragma unroll
    for (int mi = 0; mi < MI; ++mi){
      #pragma unroll
      for (int rg = 0; rg < 4; ++rg){
        int rowg = m0 + wr*(BM/NWM) + (mi << 4) + (qq << 2) + rg;
        float v = acc[mi][ni][rg] + bb;
        if (mode == 1){
          // gelu(tanh approx): v - v/(exp(1.5957691*(v+0.044715 v^3)) + 1)
          float z = 1.5957691216057308f * (v + 0.044715f*v*v*v);
          v = v - v / (__expf(z) + 1.0f);
        }
        if (mode == 2){
          Cf[(size_t)rowg*N + col] += v;
        } else {
          Cb[(size_t)rowg*N + col] = f2bf(v);
        }
      }
    }
  }
}

// ---------------- flash attention fwd ----------------------------------------
// One q-tile (64 rows) of one (b,h).
DEVINL void attn_tile(const u16* __restrict__ qkv, const u16* __restrict__ vt,
                      u16* __restrict__ o, int qt, int b, int h,
                      u16* Ks, u16* Vs, u16* Ps){
  const int tid = threadIdx.x, lane = tid & 63, w = tid >> 6;
  const int r = lane & 15, qq = lane >> 4;
  const int qrow0 = (qt << 6) + (w << 4);

  const u16* qp = qkv + (size_t)(b*1024 + qrow0 + r)*3072 + h*64 + (qq << 3);
  bf16x8 qf0 = *(const bf16x8*)qp;          // hd qq*8..+8
  bf16x8 qf1 = *(const bf16x8*)(qp + 32);   // hd 32+qq*8..+8

  const f32x4 vzero = {0.f, 0.f, 0.f, 0.f};
  float m_run[4], l_run[4];
  f32x4 acc_o[4];
  #pragma unroll
  for (int i = 0; i < 4; ++i){ m_run[i] = -1e30f; l_run[i] = 0.0f; acc_o[i] = vzero; }
  const float slope = exp2f(-0.5f*(float)(h + 1));   // ALiBi slopes for H=16

  for (int jt = 0; jt <= qt; ++jt){
    const int kv0 = jt << 6;
    __syncthreads();   // previous tile's K/V reads done
    #pragma unroll
    for (int e = 0; e < 2; ++e){
      int idx = (e << 8) + tid;
      int row = idx >> 3, ch = idx & 7;
      *(bf16x8*)&Ks[row*72 + (ch << 3)] =
        *(const bf16x8*)(qkv + (size_t)(b*1024 + kv0 + row)*3072 + 1024 + h*64 + (ch << 3));
      *(bf16x8*)&Vs[row*72 + (ch << 3)] =
        *(const bf16x8*)(vt + (size_t)(h*64 + row)*2048 + b*1024 + kv0 + (ch << 3));
    }
    __syncthreads();

    // S = Q K^T  (per wave: 16 q-rows x 64 kv)
    f32x4 sa[4];
    __builtin_amdgcn_s_setprio(1);
    #pragma unroll
    for (int ni = 0; ni < 4; ++ni){
      f32x4 z = vzero;
      bf16x8 kf0 = *(const bf16x8*)&Ks[(ni*16 + r)*72 + (qq << 3)];
      bf16x8 kf1 = *(const bf16x8*)&Ks[(ni*16 + r)*72 + 32 + (qq << 3)];
      z = __builtin_amdgcn_mfma_f32_16x16x32_bf16(qf0, kf0, z, 0, 0, 0);
      z = __builtin_amdgcn_mfma_f32_16x16x32_bf16(qf1, kf1, z, 0, 0, 0);
      sa[ni] = z;
    }
    __builtin_amdgcn_s_setprio(0);
    // scale + alibi (col-only) + clamp + causal mask
    float mx[4] = {-1e30f, -1e30f, -1e30f, -1e30f};
    #pragma unroll
    for (int ni = 0; ni < 4; ++ni){
      int colg = kv0 + ni*16 + r;
      float ab = -slope * (float)(1023 - colg);
      #pragma unroll
      for (int rg = 0; rg < 4; ++rg){
        int rowg = (qt << 6) + (w << 4) + (qq << 2) + rg;
        float sv = sa[ni][rg]*0.125f + ab;
        sv = fminf(sv, 60.0f);             // NaN firewall; legit scores << 60
        sv = (colg > rowg) ? -1e30f : sv;
        sa[ni][rg] = sv;
        mx[rg] = fmaxf(mx[rg], sv);
      }
    }
    #pragma unroll
    for (int off = 1; off < 16; off <<= 1){
      #pragma unroll
      for (int rg = 0; rg < 4; ++rg) mx[rg] = fmaxf(mx[rg], __shfl_xor(mx[rg], off));
    }
    float alpha[4], rs[4];
    #pragma unroll
    for (int rg = 0; rg < 4; ++rg){
      float mn = fmaxf(m_run[rg], mx[rg]);
      alpha[rg] = __expf(m_run[rg] - mn);
      m_run[rg] = mn;
      rs[rg] = 0.0f;
    }
    u16* pw = Ps;
    #pragma unroll
    for (int ni = 0; ni < 4; ++ni){
      #pragma unroll
      for (int rg = 0; rg < 4; ++rg){
        float p = __expf(sa[ni][rg] - m_run[rg]);
        rs[rg] += p;
        pw[(qq*4 + rg)*72 + ni*16 + r] = f2bf(p);   // P[qrow][kv], wave-local
      }
    }
    #pragma unroll
    for (int off = 1; off < 16; off <<= 1){
      #pragma unroll
      for (int rg = 0; rg < 4; ++rg) rs[rg] += __shfl_xor(rs[rg], off);
    }
    #pragma unroll
    for (int rg = 0; rg < 4; ++rg) l_run[rg] = l_run[rg]*alpha[rg] + rs[rg];
    #pragma unroll
    for (int ni = 0; ni < 4; ++ni)
      #pragma unroll
      for (int rg = 0; rg < 4; ++rg) acc_o[ni][rg] *= alpha[rg];
    __syncthreads();   // P stores visible before vector reload (ordering guard)
    // O += P V   (A = P from LDS, B = V^T rows -> k-contiguous)
    __builtin_amdgcn_s_setprio(1);
    #pragma unroll
    for (int kk = 0; kk < 2; ++kk){
      bf16x8 pa = *(const bf16x8*)&pw[r*72 + (kk << 5) + (qq << 3)];
      #pragma unroll
      for (int ni = 0; ni < 4; ++ni){
        bf16x8 vf = *(const bf16x8*)&Vs[(ni*16 + r)*72 + (kk << 5) + (qq << 3)];
        acc_o[ni] = __builtin_amdgcn_mfma_f32_16x16x32_bf16(pa, vf, acc_o[ni], 0, 0, 0);
      }
    }
    __builtin_amdgcn_s_setprio(0);
  }
  #pragma unroll
  for (int ni = 0; ni < 4; ++ni){
    #pragma unroll
    for (int rg = 0; rg < 4; ++rg){
      int rowg = b*1024 + (qt << 6) + (w << 4) + (qq << 2) + rg;
      o[(size_t)rowg*1024 + h*64 + ni*16 + r] = f2bf(acc_o[ni][rg] / l_run[rg]);
    }
  }
}

// grid (16,32) = 512 blocks, 2/CU co-resident. Complementary pairing: blocks
// c and c+256 (which share a CU per round-16 evidence) get q-tiles p and 15-p
// of the same bh set -> every CU totals 17 KV-tile-units at 8 waves/CU.
__global__ __launch_bounds__(256) void attn_kernel(const u16* __restrict__ qkv,
    const u16* __restrict__ vt, u16* __restrict__ o){
  const int flat = blockIdx.y * 16 + blockIdx.x;   // 0..511
  const int hi = flat >> 8;                        // 0 or 1
  const int i  = flat & 255;
  const int bh = i & 31;
  const int p  = i >> 5;                           // 0..7
  const int qt = hi ? (15 - p) : p;
  const int b = bh >> 4, h = bh & 15;
  const int w = threadIdx.x >> 6;
  __shared__ alignas(16) u16 Ks[64*72];     // K tile [kv][hd], pad 8
  __shared__ alignas(16) u16 Vs[64*72];     // V^T tile [hd][kv], pad 8
  __shared__ alignas(16) u16 Ps[4][16*72];  // per-wave P [qrow][kv]
  attn_tile(qkv, vt, o, qt, b, h, Ks, Vs, &Ps[w][0]);
}

// ---------------- driver ------------------------------------------------------
extern "C" void kernel_launch(void* const* d_in, const int* in_sizes, int n_in,
                              void* d_out, int out_size, void* d_ws, size_t ws_size,
                              hipStream_t stream){
  (void)in_sizes; (void)n_in; (void)out_size;
  const int*   tok  = (const int*)d_in[0];
  const float* wte  = (const float*)d_in[1];
  const float* ln1s = (const float*)d_in[2];
  const float* ln1b = (const float*)d_in[3];
  const float* Wq   = (const float*)d_in[4];
  const float* bq   = (const float*)d_in[5];
  const float* Wk   = (const float*)d_in[6];
  const float* bk   = (const float*)d_in[7];
  const float* Wv   = (const float*)d_in[8];
  const float* bv   = (const float*)d_in[9];
  const float* Wo   = (const float*)d_in[10];
  const float* bo   = (const float*)d_in[11];
  const float* ln2s = (const float*)d_in[12];
  const float* ln2b = (const float*)d_in[13];
  const float* Wfi  = (const float*)d_in[14];
  const float* bfi  = (const float*)d_in[15];
  const float* Wfo  = (const float*)d_in[16];
  const float* bfo  = (const float*)d_in[17];
  const float* lnfs = (const float*)d_in[18];
  const float* lnfb = (const float*)d_in[19];

  char* ws = (char*)d_ws;
  float* x   = (float*)(ws);
  u16* h     = (u16*)(ws + ( 8u << 20));
  u16* qkv   = (u16*)(ws + (12u << 20));
  u16* v_t   = (u16*)(ws + (24u << 20));
  u16* attnb = (u16*)(ws + (28u << 20));
  u16* ffn   = (u16*)(ws + (32u << 20));
  u16* wT    = (u16*)(ws + (48u << 20));
  float* b3  = (float*)(ws + (56u << 20));
  u16* wteb  = (u16*)(ws + (57u << 20));

  const size_t wteb_bytes = (size_t)50257 * 1024 * 2;
  const bool big_ws = ws_size >= ((size_t)(57u) << 20) + wteb_bytes;

  if (big_ws){
    // convert wte to bf16 once (51,463,168 elems = 6,432,896 lanes of 8)
    cvt_bf16_kernel<<<25129, 256, 0, stream>>>(wte, wteb, 6432896);
  }
  embed_kernel<<<2048, 256, 0, stream>>>(tok, wte, x);
  concat_all_kernel<<<48, 256, 0, stream>>>(bq, bk, bv, b3);
  for (int i = 0; i < 4; ++i){
    ln_kernel<<<2048, 256, 0, stream>>>(x, ln1s + i*1024, ln1b + i*1024, h);
    transpose3_kernel<<<dim3(16,16,3), 256, 0, stream>>>(
        Wq + (size_t)i*1048576, Wk + (size_t)i*1048576, Wv + (size_t)i*1048576, wT);
    gemm_nt<false,128,128,2,2><<<dim3(24,16), 256, 0, stream>>>(h, wT, b3 + i*3072, qkv, nullptr, 3072, 1024, 0);
    transpose_kernel<u16><<<dim3(16,32), 256, 0, stream>>>(qkv + 2048, v_t, 3072, 2048);
    attn_kernel<<<dim3(16,32), 256, 0, stream>>>(qkv, v_t, attnb);
    transpose_kernel<float><<<dim3(16,16), 256, 0, stream>>>(Wo + (size_t)i*1048576, wT, 1024, 1024);
    gemm_nt<false,64,64,2,2><<<dim3(16,32), 256, 0, stream>>>(attnb, wT, bo + i*1024, nullptr, x, 1024, 1024, 2);
    ln_kernel<<<2048, 256, 0, stream>>>(x, ln2s + i*1024, ln2b + i*1024, h);
    transpose_kernel<float><<<dim3(64,16), 256, 0, stream>>>(Wfi + (size_t)i*4194304, wT, 4096, 1024);
    gemm_nt<false,128,256,2,4><<<dim3(16,16), 512, 0, stream>>>(h, wT, bfi + i*4096, ffn, nullptr, 4096, 1024, 1);
    transpose_kernel<float><<<dim3(16,64), 256, 0, stream>>>(Wfo + (size_t)i*4194304, wT, 1024, 4096);
    gemm_nt<false,64,64,2,2><<<dim3(16,32), 256, 0, stream>>>(ffn, wT, bfo + i*1024, nullptr, x, 1024, 4096, 2);
  }
  ln_kernel<<<2048, 256, 0, stream>>>(x, lnfs, lnfb, h);
  if (big_ws){
    gemm_nt<false,128,256,2,4><<<dim3(197,16), 512, 0, stream>>>(h, wteb, nullptr, nullptr, (float*)d_out, 50257, 1024, 3);
  } else {
    gemm_nt<true,128,128,2,2><<<dim3(393,16), 256, 0, stream>>>(h, wte, nullptr, nullptr, (float*)d_out, 50257, 1024, 3);
  }
}

// Round 21
// 1109.950 us; speedup vs baseline: 1.0416x; 1.0012x over previous
//
#include <hip/hip_runtime.h>
#include <hip/hip_bf16.h>

// Transformer forward, MI355X gfx950.  (Round 21 = verbatim revert to the
// round-19 best-passing state; round-20's DEPTH=6 pipeline NaN'd — >6
// outstanding global_load_lds per wave is outside every validated envelope.)
// Inputs/outputs are FLOAT32 (per reference). bf16 is used only as the MFMA
// compute format; residual stream, LN, softmax, biases, logits all f32.
// Workspace layout (bytes):
//   x     f32 [2048][1024]   @ 0      (8 MB)   residual stream
//   h     bf16[2048][1024]   @ 8 MB   (4 MB)   LN outputs
//   qkv   bf16[2048][3072]   @ 12 MB  (12 MB)
//   v_t   bf16[1024][2048]   @ 24 MB  (4 MB)   V transposed for attention
//   attn  bf16[2048][1024]   @ 28 MB  (4 MB)
//   ffn   bf16[2048][4096]   @ 32 MB  (16 MB)
//   wT    bf16 (<=8 MB)      @ 48 MB  (8 MB)   transposed+converted weights
//   b3    f32 [4][3072]      @ 56 MB  (48 KB)  all-layer qkv bias
//   wteb  bf16[50257][1024]  @ 57 MB  (103 MB) bf16 copy of wte (if ws fits)
//
// Round 11/12: per-WAVE acc must stay <= 64 regs (8-wave fat tiles).
// Round 16/17: attention uses COMPLEMENTARY qt pairing (p with 15-p) =>
// 17 tile-units per CU, 8 waves/CU.
// Round 18/19: BM=64 only where CUs were at 4 waves (attn-out, ffn2).
// Round 20 lesson: keep pipeline depth at 3 (<=2 stages / <=4 loads in
// flight per wave with gload_lds) — deeper counted-vmcnt windows corrupt.

typedef unsigned short u16;
typedef unsigned int u32;
typedef __attribute__((ext_vector_type(8))) short bf16x8;   // 8 bf16 = 4 VGPR
typedef __attribute__((ext_vector_type(4))) float f32x4;

#define DEVINL static __device__ __forceinline__
#define WAITVM(N) asm volatile("s_waitcnt vmcnt(" #N ")" ::: "memory")

DEVINL u16 f2bf(float f){ __hip_bfloat16 h = __float2bfloat16(f); return *reinterpret_cast<u16*>(&h); }

DEVINL bf16x8 cvt8(float4 a, float4 b){
  bf16x8 r;
  r[0] = (short)f2bf(a.x); r[1] = (short)f2bf(a.y);
  r[2] = (short)f2bf(a.z); r[3] = (short)f2bf(a.w);
  r[4] = (short)f2bf(b.x); r[5] = (short)f2bf(b.y);
  r[6] = (short)f2bf(b.z); r[7] = (short)f2bf(b.w);
  return r;
}

DEVINL void gload16(const u16* g, u16* l){
  // async global->LDS: per-lane GLOBAL source, wave-uniform LDS base + lane*16
  __builtin_amdgcn_global_load_lds((const __attribute__((address_space(1))) void*)g,
                                   (__attribute__((address_space(3))) void*)l, 16, 0, 0);
}

// ---------------- f32 -> bf16 bulk convert (8 elems/lane) --------------------
__global__ __launch_bounds__(256) void cvt_bf16_kernel(const float* __restrict__ src,
    u16* __restrict__ dst, int n8){
  int i = blockIdx.x*256 + threadIdx.x;
  if (i >= n8) return;
  const float4* p = (const float4*)(src + (size_t)i*8);
  float4 a = p[0], b = p[1];
  *(bf16x8*)(dst + (size_t)i*8) = cvt8(a, b);
}

// ---------------- embedding gather: x[m][:] = wte[tok[m]][:] (f32 copy) ------
__global__ __launch_bounds__(256) void embed_kernel(const int* __restrict__ tok,
    const float* __restrict__ wte, float* __restrict__ x){
  int m = blockIdx.x, t = threadIdx.x;
  int token = tok[m];
  float4 f = ((const float4*)(wte + (size_t)token*1024))[t];
  ((float4*)(x + (size_t)m*1024))[t] = f;
}

// ---------------- LayerNorm: f32 in, bf16 out, one row per block -------------
__global__ __launch_bounds__(256) void ln_kernel(const float* __restrict__ x,
    const float* __restrict__ gam, const float* __restrict__ bet, u16* __restrict__ out){
  int m = blockIdx.x, t = threadIdx.x;
  float4 v = ((const float4*)(x + (size_t)m*1024))[t];
  float s  = v.x + v.y + v.z + v.w;
  float s2 = v.x*v.x + v.y*v.y + v.z*v.z + v.w*v.w;
  #pragma unroll
  for (int o = 32; o > 0; o >>= 1){ s += __shfl_xor(s, o); s2 += __shfl_xor(s2, o); }
  __shared__ float red[8];
  int w = t >> 6;
  if ((t & 63) == 0){ red[w] = s; red[4 + w] = s2; }
  __syncthreads();
  s  = red[0] + red[1] + red[2] + red[3];
  s2 = red[4] + red[5] + red[6] + red[7];
  float mean = s * (1.0f/1024.0f);
  float var  = s2 * (1.0f/1024.0f) - mean*mean;
  float inv  = rsqrtf(var + 1e-6f);
  float4 gv = ((const float4*)gam)[t];
  float4 bv = ((const float4*)bet)[t];
  u32 o0 = f2bf((v.x - mean)*inv*gv.x + bv.x);
  u32 o1 = f2bf((v.y - mean)*inv*gv.y + bv.y);
  u32 o2 = f2bf((v.z - mean)*inv*gv.z + bv.z);
  u32 o3 = f2bf((v.w - mean)*inv*gv.w + bv.w);
  uint2 ov; ov.x = o0 | (o1 << 16); ov.y = o2 | (o3 << 16);
  ((uint2*)(out + (size_t)m*1024))[t] = ov;
}

// ---------------- transpose core: 64x64 tile, src f32 or u16 -----------------
template<typename T>
DEVINL void transpose_tile(const T* __restrict__ src, u16* __restrict__ dst,
                           int ss, int ds, int c0, int r0, int t){
  __shared__ alignas(16) u16 tile[64][68];
  #pragma unroll
  for (int e = 0; e < 4; ++e){
    int idx = (e << 8) + t;
    int r = idx >> 4, c = (idx & 15) << 2;
    if constexpr (sizeof(T) == 4){
      float4 f = *(const float4*)(src + (size_t)(r0 + r)*ss + c0 + c);
      tile[r][c+0] = f2bf(f.x); tile[r][c+1] = f2bf(f.y);
      tile[r][c+2] = f2bf(f.z); tile[r][c+3] = f2bf(f.w);
    } else {
      uint2 u = *(const uint2*)(src + (size_t)(r0 + r)*ss + c0 + c);
      tile[r][c+0] = (u16)(u.x & 0xffffu); tile[r][c+1] = (u16)(u.x >> 16);
      tile[r][c+2] = (u16)(u.y & 0xffffu); tile[r][c+3] = (u16)(u.y >> 16);
    }
  }
  __syncthreads();
  #pragma unroll
  for (int e = 0; e < 4; ++e){
    int idx = (e << 8) + t;
    int cc = idx >> 4, rr = (idx & 15) << 2;
    uint2 u;
    u.x = (u32)tile[rr+0][cc] | ((u32)tile[rr+1][cc] << 16);
    u.y = (u32)tile[rr+2][cc] | ((u32)tile[rr+3][cc] << 16);
    *(uint2*)(dst + (size_t)(c0 + cc)*ds + r0 + rr) = u;
  }
}

template<typename T>
__global__ __launch_bounds__(256) void transpose_kernel(const T* __restrict__ src,
    u16* __restrict__ dst, int ss, int ds){
  transpose_tile<T>(src, dst, ss, ds, blockIdx.x << 6, blockIdx.y << 6, threadIdx.x);
}

// 3 square 1024x1024 f32 weights -> bf16 transposed, z selects the matrix
__global__ __launch_bounds__(256) void transpose3_kernel(const float* __restrict__ s0,
    const float* __restrict__ s1, const float* __restrict__ s2, u16* __restrict__ dst){
  const float* src = (blockIdx.z == 0) ? s0 : ((blockIdx.z == 1) ? s1 : s2);
  transpose_tile<float>(src, dst + (size_t)blockIdx.z*1048576, 1024, 1024,
                        blockIdx.x << 6, blockIdx.y << 6, threadIdx.x);
}

// ---------------- concat qkv biases for ALL layers -> b3[4][3072] ------------
__global__ __launch_bounds__(256) void concat_all_kernel(const float* __restrict__ bq,
    const float* __restrict__ bk, const float* __restrict__ bv, float* __restrict__ o){
  int g = blockIdx.x*256 + threadIdx.x;      // 0..12287
  int l = g / 3072, j = g % 3072;
  float v;
  if (j < 1024)      v = bq[l*1024 + j];
  else if (j < 2048) v = bk[l*1024 + j - 1024];
  else               v = bv[l*1024 + j - 2048];
  o[g] = v;
}

// ---------------- NT bf16 GEMM: C[m][n] = sum_k A[m][k]*B[n][k] ---------------
// BM x BN tile, BK=32, NWM x NWC waves (wave owns BM/NWM x BN/NWC), 16x16x32.
// bf16 path: 3-deep pipeline: 3 LDS buffers, STAGE(t+2) at t, counted
// s_waitcnt vmcnt(LW) + raw s_barrier. T2 swizzle: global source unit XOR
// ((lane>>3)&3), LDS dest linear, read unit qq ^ ((r>>1)&3).
// BF32 fallback (128/128/2/2 only): 2-buffer __syncthreads.
// XCD-chunked, m-inner block remap (B-panel reused (2048/BM)x from L2).
// mode 0: Cb=bf16(acc+bias); 1: Cb=bf16(gelu); 2: Cf+=acc+bias;
// mode 3: Cf=acc -- LDS-staged, 64B-aligned regular stores (no NT: round 9).
template<bool BF32, int BM, int BN, int NWM, int NWC>
__global__ __launch_bounds__(NWM*NWC*64) void gemm_nt(const u16* __restrict__ A,
    const void* __restrict__ Bp, const float* __restrict__ bias,
    u16* __restrict__ Cb, float* __restrict__ Cf,
    int N, int K, int mode){
  constexpr int NWAVES = NWM*NWC;
  constexpr int MI = BM / NWM / 16;           // per-wave m fragments
  constexpr int NI = BN / NWC / 16;           // per-wave n fragments
  constexpr int RPC = NWAVES*16;              // rows per stage line-call
  constexpr int ALC = BM / RPC;               // A line-calls per stage
  constexpr int BLC = BN / RPC;               // B line-calls per stage
  constexpr int LW  = ALC + BLC;              // loads in flight per stage
  constexpr int CHUNK = NWAVES*512;           // u16 per line-call
  constexpr int ASTR = BM*32;                 // u16 per A buffer
  constexpr int BSTR = BN*32;                 // u16 per B buffer
  constexpr int BUFSZ = ASTR + BSTR;
  constexpr int NBUF = BF32 ? 2 : 3;
  constexpr int MT  = 2048 / BM;              // m-tiles (gridDim.y)
  __shared__ alignas(16) u16 S[NBUF*BUFSZ];
  const int tid = threadIdx.x, lane = tid & 63, w = tid >> 6;
  const int wr = w / NWC, wc = w % NWC;
  // ---- XCD-chunked (bijective), m-inner remap ----
  const int nx = gridDim.x;
  const int nwg = nx * MT;
  const int flat = blockIdx.y * nx + blockIdx.x;
  const int qch = nwg >> 3, rch = nwg & 7;
  const int xcd = flat & 7, idxc = flat >> 3;
  const int nf = (xcd < rch ? xcd*(qch+1) : rch*(qch+1) + (xcd-rch)*qch) + idxc;
  const int m0 = (nf & (MT-1)) * BM;
  const int n0 = (nf / MT) * BN;
  const int r = lane & 15, qq = lane >> 4;
  const int srow = (w << 4) + (lane >> 2);    // staging row within a line-call
  const int sus  = lane & 3;                  // linear 16B unit within row
  const int su2  = sus ^ ((lane >> 3) & 3);   // swizzled global-source unit
  const int rsw  = (r >> 1) & 3;              // read-side swizzle term
  const f32x4 vzero = {0.f, 0.f, 0.f, 0.f};
  f32x4 acc[MI][NI];
  #pragma unroll
  for (int i = 0; i < MI; ++i)
    #pragma unroll
    for (int j = 0; j < NI; ++j) acc[i][j] = vzero;

  // staging source pointers at k=0
  const u16* pa[ALC];
  #pragma unroll
  for (int i = 0; i < ALC; ++i)
    pa[i] = A + (size_t)(m0 + i*RPC + srow)*K + (su2 << 3);
  const u16* pb[BLC > 0 ? BLC : 1];
  const float* pbf0 = nullptr; const float* pbf1 = nullptr;
  if constexpr (BF32){
    int nr0 = n0 + srow;      if (nr0 >= N) nr0 = N - 1;
    int nr1 = n0 + 64 + srow; if (nr1 >= N) nr1 = N - 1;
    pbf0 = (const float*)Bp + (size_t)nr0*K + (sus << 3);
    pbf1 = (const float*)Bp + (size_t)nr1*K + (sus << 3);
  } else {
    #pragma unroll
    for (int i = 0; i < BLC; ++i){
      int nr = n0 + i*RPC + srow; if (nr >= N) nr = N - 1;
      pb[i] = (const u16*)Bp + (size_t)nr*K + (su2 << 3);
    }
  }

  const int nkt = K >> 5;                      // >= 2 for all our shapes

#define GEMM_STAGE(dst, kofs) do {                                        \
    _Pragma("unroll")                                                     \
    for (int i = 0; i < ALC; ++i)                                         \
      gload16(pa[i] + (kofs), &(dst)[i*CHUNK + (w << 9)]);                \
    _Pragma("unroll")                                                     \
    for (int i = 0; i < BLC; ++i)                                         \
      gload16(pb[i] + (kofs), &(dst)[ASTR + i*CHUNK + (w << 9)]);         \
  } while(0)
#define GEMM_WAIT_LW() do {                                               \
    if constexpr (LW == 2) { WAITVM(2); }                                 \
    else if constexpr (LW == 3) { WAITVM(3); }                            \
    else if constexpr (LW == 4) { WAITVM(4); }                            \
    else { WAITVM(6); }                                                   \
  } while(0)
#define GEMM_COMPUTE(rdbuf) do {                                          \
    bf16x8 af[MI], bfv[NI];                                               \
    _Pragma("unroll")                                                     \
    for (int mi = 0; mi < MI; ++mi){                                      \
      int rowi = wr*(BM/NWM) + (mi << 4) + r;                             \
      af[mi] = *(const bf16x8*)&(rdbuf)[(rowi << 5) + ((qq ^ rsw) << 3)]; \
    }                                                                     \
    _Pragma("unroll")                                                     \
    for (int ni = 0; ni < NI; ++ni){                                      \
      int rowi = wc*(BN/NWC) + (ni << 4) + r;                             \
      bfv[ni] = *(const bf16x8*)&(rdbuf)[ASTR + (rowi << 5) + ((qq ^ rsw) << 3)]; \
    }                                                                     \
    _Pragma("unroll")                                                     \
    for (int mi = 0; mi < MI; ++mi)                                       \
      _Pragma("unroll")                                                   \
      for (int ni = 0; ni < NI; ++ni)                                     \
        acc[mi][ni] = __builtin_amdgcn_mfma_f32_16x16x32_bf16(af[mi], bfv[ni], acc[mi][ni], 0, 0, 0); \
  } while(0)

  if constexpr (!BF32){
    u16 *rd = S, *nxt = S + BUFSZ, *st = S + 2*BUFSZ;
    GEMM_STAGE(rd, 0);
    GEMM_STAGE(nxt, 32);
    GEMM_WAIT_LW();
    __builtin_amdgcn_sched_barrier(0);
    __builtin_amdgcn_s_barrier();
    __builtin_amdgcn_sched_barrier(0);
    for (int kt = 0; kt < nkt; ++kt){
      const bool more2 = (kt + 2 < nkt);
      if (more2){ GEMM_STAGE(st, (kt + 2) << 5); }
      GEMM_COMPUTE(rd);
      if (kt + 1 < nkt){
        if (more2){ GEMM_WAIT_LW(); } else { WAITVM(0); }
        __builtin_amdgcn_sched_barrier(0);
        __builtin_amdgcn_s_barrier();
        __builtin_amdgcn_sched_barrier(0);
        u16* t0 = rd; rd = nxt; nxt = st; st = t0;
      }
    }
  } else {
    // ---- BF32 fallback (128/128, 4 waves): 2-buffer, __syncthreads ----
    const int sw0 = (srow << 5) + (sus << 3);
    const int sw1 = ((srow + 64) << 5) + (sus << 3);
    {
      u16* Ab = S; u16* Bb = S + ASTR;
      #pragma unroll
      for (int i = 0; i < ALC; ++i) gload16(pa[i], &Ab[i*CHUNK + (w << 9)]);
      float4 g0 = *(const float4*)pbf0, g1 = *(const float4*)(pbf0 + 4);
      float4 g2 = *(const float4*)pbf1, g3 = *(const float4*)(pbf1 + 4);
      *(bf16x8*)&Bb[sw0] = cvt8(g0, g1);
      *(bf16x8*)&Bb[sw1] = cvt8(g2, g3);
      __syncthreads();
    }
    int buf = 0;
    for (int kt = 0; kt < nkt; ++kt){
      u16* Ab = S + buf*BUFSZ;
      u16* Bb = Ab + ASTR;
      const int nb = buf ^ 1;
      u16* An = S + nb*BUFSZ;
      u16* Bn = An + ASTR;
      float4 g0, g1, g2, g3;
      const bool more = (kt + 1 < nkt);
      if (more){
        const int k1 = (kt + 1) << 5;
        #pragma unroll
        for (int i = 0; i < ALC; ++i) gload16(pa[i] + k1, &An[i*CHUNK + (w << 9)]);
        g0 = *(const float4*)(pbf0 + k1); g1 = *(const float4*)(pbf0 + k1 + 4);
        g2 = *(const float4*)(pbf1 + k1); g3 = *(const float4*)(pbf1 + k1 + 4);
      }
      bf16x8 af[MI], bfv[NI];
      #pragma unroll
      for (int mi = 0; mi < MI; ++mi){
        int rowi = wr*(BM/NWM) + (mi << 4) + r;
        af[mi] = *(const bf16x8*)&Ab[(rowi << 5) + ((qq ^ rsw) << 3)];  // A swizzled
      }
      #pragma unroll
      for (int ni = 0; ni < NI; ++ni){
        int rowi = wc*(BN/NWC) + (ni << 4) + r;
        bfv[ni] = *(const bf16x8*)&Bb[(rowi << 5) + (qq << 3)];         // B linear
      }
      #pragma unroll
      for (int mi = 0; mi < MI; ++mi)
        #pragma unroll
        for (int ni = 0; ni < NI; ++ni)
          acc[mi][ni] = __builtin_amdgcn_mfma_f32_16x16x32_bf16(af[mi], bfv[ni], acc[mi][ni], 0, 0, 0);
      if (more){
        *(bf16x8*)&Bn[sw0] = cvt8(g0, g1);
        *(bf16x8*)&Bn[sw1] = cvt8(g2, g3);
      }
      __syncthreads();
      buf = nb;
    }
  }
#undef GEMM_STAGE
#undef GEMM_WAIT_LW
#undef GEMM_COMPUTE

  // ---- mode 3 (f32 store, no bias/act): LDS-staged, 64B-aligned stores ----
  if constexpr (BN == 128 && NWC == 2){
    if (mode == 3){
      float* ep = (float*)S;                 // 2 regions x 16 rows x 132 f32
      const int row16 = tid >> 3;            // 0..31
      const int wr2 = row16 >> 4, rr = row16 & 15;
      const int q8 = tid & 7;
      #pragma unroll
      for (int c = 0; c < MI; ++c){
        __syncthreads();
        #pragma unroll
        for (int ni = 0; ni < NI; ++ni)
          #pragma unroll
          for (int rg = 0; rg < 4; ++rg)
            ep[wr*2112 + ((qq << 2) + rg)*132 + wc*64 + (ni << 4) + r] = acc[c][ni][rg];
        __syncthreads();
        const float* src = &ep[wr2*2112 + rr*132];
        const int grow = m0 + wr2*(BM/2) + (c << 4) + rr;
        const size_t basef = (size_t)grow*N + n0;
        const int al = (int)((16 - (basef & 15)) & 15);
        if (q8 < 7){
          const int c0 = al + (q8 << 4);
          float* dst = &Cf[basef + c0];
          if (n0 + c0 + 15 < N){
            #pragma unroll
            for (int qk = 0; qk < 4; ++qk){
              f32x4 v;
              v[0] = src[c0 + qk*4 + 0]; v[1] = src[c0 + qk*4 + 1];
              v[2] = src[c0 + qk*4 + 2]; v[3] = src[c0 + qk*4 + 3];
              *(f32x4*)(dst + qk*4) = v;
            }
          } else {
            for (int i = 0; i < 16; ++i)
              if (n0 + c0 + i < N) dst[i] = src[c0 + i];
          }
        } else {
          for (int i = 0; i < al; ++i)
            if (n0 + i < N) Cf[basef + i] = src[i];
          for (int i = al + 112; i < 128; ++i)
            if (n0 + i < N) Cf[basef + i] = src[i];
        }
      }
      return;
    }
  }
  if constexpr (BN == 256 && NWC == 4){
    if (mode == 3){
      // 2 regions x 16 rows x 260 f32; 512 threads, 16 threads/row
      float* ep = (float*)S;
      const int row16 = tid >> 4;            // 0..31
      const int wr2 = row16 >> 4, rr = row16 & 15;
      const int q16 = tid & 15;
      #pragma unroll
      for (int c = 0; c < MI; ++c){
        __syncthreads();
        #pragma unroll
        for (int ni = 0; ni < NI; ++ni)
          #pragma unroll
          for (int rg = 0; rg < 4; ++rg)
            ep[wr*4160 + ((qq << 2) + rg)*260 + wc*64 + (ni << 4) + r] = acc[c][ni][rg];
        __syncthreads();
        const float* src = &ep[wr2*4160 + rr*260];
        const int grow = m0 + wr2*(BM/2) + (c << 4) + rr;
        const size_t basef = (size_t)grow*N + n0;
        const int al = (int)((16 - (basef & 15)) & 15);
        if (q16 < 15){
          const int c0 = al + (q16 << 4);
          float* dst = &Cf[basef + c0];
          if (n0 + c0 + 15 < N){
            #pragma unroll
            for (int qk = 0; qk < 4; ++qk){
              f32x4 v;
              v[0] = src[c0 + qk*4 + 0]; v[1] = src[c0 + qk*4 + 1];
              v[2] = src[c0 + qk*4 + 2]; v[3] = src[c0 + qk*4 + 3];
              *(f32x4*)(dst + qk*4) = v;
            }
          } else {
            for (int i = 0; i < 16; ++i)
              if (n0 + c0 + i < N) dst[i] = src[c0 + i];
          }
        } else {
          for (int i = 0; i < al; ++i)                 // ragged head
            if (n0 + i < N) Cf[basef + i] = src[i];
          for (int i = al + 240; i < 256; ++i)         // ragged tail
            if (n0 + i < N) Cf[basef + i] = src[i];
        }
      }
      return;
    }
  }

  // ---- generic epilogue (modes 0,1,2): C/D layout col=lane&15, row=(lane>>4)*4+reg
  #pragma unroll
  for (int ni = 0; ni < NI; ++ni){
    int col = n0 + wc*(BN/NWC) + (ni << 4) + r;
    if (col >= N) continue;
    float bb = bias ? bias[col] : 0.0f;
    #pragma unroll
    for (int mi = 0; mi < MI; ++mi){
      #pragma unroll
      for (int rg = 0; rg < 4; ++rg){
        int rowg = m0 + wr*(BM/NWM) + (mi << 4) + (qq << 2) + rg;
        float v = acc[mi][ni][rg] + bb;
        if (mode == 1){
          // gelu(tanh approx): v - v/(exp(1.5957691*(v+0.044715 v^3)) + 1)
          float z = 1.5957691216057308f * (v + 0.044715f*v*v*v);
          v = v - v / (__expf(z) + 1.0f);
        }
        if (mode == 2){
          Cf[(size_t)rowg*N + col] += v;
        } else {
          Cb[(size_t)rowg*N + col] = f2bf(v);
        }
      }
    }
  }
}

// ---------------- flash attention fwd ----------------------------------------
// One q-tile (64 rows) of one (b,h).
DEVINL void attn_tile(const u16* __restrict__ qkv, const u16* __restrict__ vt,
                      u16* __restrict__ o, int qt, int b, int h,
                      u16* Ks, u16* Vs, u16* Ps){
  const int tid = threadIdx.x, lane = tid & 63, w = tid >> 6;
  const int r = lane & 15, qq = lane >> 4;
  const int qrow0 = (qt << 6) + (w << 4);

  const u16* qp = qkv + (size_t)(b*1024 + qrow0 + r)*3072 + h*64 + (qq << 3);
  bf16x8 qf0 = *(const bf16x8*)qp;          // hd qq*8..+8
  bf16x8 qf1 = *(const bf16x8*)(qp + 32);   // hd 32+qq*8..+8

  const f32x4 vzero = {0.f, 0.f, 0.f, 0.f};
  float m_run[4], l_run[4];
  f32x4 acc_o[4];
  #pragma unroll
  for (int i = 0; i < 4; ++i){ m_run[i] = -1e30f; l_run[i] = 0.0f; acc_o[i] = vzero; }
  const float slope = exp2f(-0.5f*(float)(h + 1));   // ALiBi slopes for H=16

  for (int jt = 0; jt <= qt; ++jt){
    const int kv0 = jt << 6;
    __syncthreads();   // previous tile's K/V reads done
    #pragma unroll
    for (int e = 0; e < 2; ++e){
      int idx = (e << 8) + tid;
      int row = idx >> 3, ch = idx & 7;
      *(bf16x8*)&Ks[row*72 + (ch << 3)] =
        *(const bf16x8*)(qkv + (size_t)(b*1024 + kv0 + row)*3072 + 1024 + h*64 + (ch << 3));
      *(bf16x8*)&Vs[row*72 + (ch << 3)] =
        *(const bf16x8*)(vt + (size_t)(h*64 + row)*2048 + b*1024 + kv0 + (ch << 3));
    }
    __syncthreads();

    // S = Q K^T  (per wave: 16 q-rows x 64 kv)
    f32x4 sa[4];
    __builtin_amdgcn_s_setprio(1);
    #pragma unroll
    for (int ni = 0; ni < 4; ++ni){
      f32x4 z = vzero;
      bf16x8 kf0 = *(const bf16x8*)&Ks[(ni*16 + r)*72 + (qq << 3)];
      bf16x8 kf1 = *(const bf16x8*)&Ks[(ni*16 + r)*72 + 32 + (qq << 3)];
      z = __builtin_amdgcn_mfma_f32_16x16x32_bf16(qf0, kf0, z, 0, 0, 0);
      z = __builtin_amdgcn_mfma_f32_16x16x32_bf16(qf1, kf1, z, 0, 0, 0);
      sa[ni] = z;
    }
    __builtin_amdgcn_s_setprio(0);
    // scale + alibi (col-only) + clamp + causal mask
    float mx[4] = {-1e30f, -1e30f, -1e30f, -1e30f};
    #pragma unroll
    for (int ni = 0; ni < 4; ++ni){
      int colg = kv0 + ni*16 + r;
      float ab = -slope * (float)(1023 - colg);
      #pragma unroll
      for (int rg = 0; rg < 4; ++rg){
        int rowg = (qt << 6) + (w << 4) + (qq << 2) + rg;
        float sv = sa[ni][rg]*0.125f + ab;
        sv = fminf(sv, 60.0f);             // NaN firewall; legit scores << 60
        sv = (colg > rowg) ? -1e30f : sv;
        sa[ni][rg] = sv;
        mx[rg] = fmaxf(mx[rg], sv);
      }
    }
    #pragma unroll
    for (int off = 1; off < 16; off <<= 1){
      #pragma unroll
      for (int rg = 0; rg < 4; ++rg) mx[rg] = fmaxf(mx[rg], __shfl_xor(mx[rg], off));
    }
    float alpha[4], rs[4];
    #pragma unroll
    for (int rg = 0; rg < 4; ++rg){
      float mn = fmaxf(m_run[rg], mx[rg]);
      alpha[rg] = __expf(m_run[rg] - mn);
      m_run[rg] = mn;
      rs[rg] = 0.0f;
    }
    u16* pw = Ps;
    #pragma unroll
    for (int ni = 0; ni < 4; ++ni){
      #pragma unroll
      for (int rg = 0; rg < 4; ++rg){
        float p = __expf(sa[ni][rg] - m_run[rg]);
        rs[rg] += p;
        pw[(qq*4 + rg)*72 + ni*16 + r] = f2bf(p);   // P[qrow][kv], wave-local
      }
    }
    #pragma unroll
    for (int off = 1; off < 16; off <<= 1){
      #pragma unroll
      for (int rg = 0; rg < 4; ++rg) rs[rg] += __shfl_xor(rs[rg], off);
    }
    #pragma unroll
    for (int rg = 0; rg < 4; ++rg) l_run[rg] = l_run[rg]*alpha[rg] + rs[rg];
    #pragma unroll
    for (int ni = 0; ni < 4; ++ni)
      #pragma unroll
      for (int rg = 0; rg < 4; ++rg) acc_o[ni][rg] *= alpha[rg];
    __syncthreads();   // P stores visible before vector reload (ordering guard)
    // O += P V   (A = P from LDS, B = V^T rows -> k-contiguous)
    __builtin_amdgcn_s_setprio(1);
    #pragma unroll
    for (int kk = 0; kk < 2; ++kk){
      bf16x8 pa = *(const bf16x8*)&pw[r*72 + (kk << 5) + (qq << 3)];
      #pragma unroll
      for (int ni = 0; ni < 4; ++ni){
        bf16x8 vf = *(const bf16x8*)&Vs[(ni*16 + r)*72 + (kk << 5) + (qq << 3)];
        acc_o[ni] = __builtin_amdgcn_mfma_f32_16x16x32_bf16(pa, vf, acc_o[ni], 0, 0, 0);
      }
    }
    __builtin_amdgcn_s_setprio(0);
  }
  #pragma unroll
  for (int ni = 0; ni < 4; ++ni){
    #pragma unroll
    for (int rg = 0; rg < 4; ++rg){
      int rowg = b*1024 + (qt << 6) + (w << 4) + (qq << 2) + rg;
      o[(size_t)rowg*1024 + h*64 + ni*16 + r] = f2bf(acc_o[ni][rg] / l_run[rg]);
    }
  }
}

// grid (16,32) = 512 blocks, 2/CU co-resident. Complementary pairing: blocks
// c and c+256 (which share a CU per round-16 evidence) get q-tiles p and 15-p
// of the same bh set -> every CU totals 17 KV-tile-units at 8 waves/CU.
__global__ __launch_bounds__(256) void attn_kernel(const u16* __restrict__ qkv,
    const u16* __restrict__ vt, u16* __restrict__ o){
  const int flat = blockIdx.y * 16 + blockIdx.x;   // 0..511
  const int hi = flat >> 8;                        // 0 or 1
  const int i  = flat & 255;
  const int bh = i & 31;
  const int p  = i >> 5;                           // 0..7
  const int qt = hi ? (15 - p) : p;
  const int b = bh >> 4, h = bh & 15;
  const int w = threadIdx.x >> 6;
  __shared__ alignas(16) u16 Ks[64*72];     // K tile [kv][hd], pad 8
  __shared__ alignas(16) u16 Vs[64*72];     // V^T tile [hd][kv], pad 8
  __shared__ alignas(16) u16 Ps[4][16*72];  // per-wave P [qrow][kv]
  attn_tile(qkv, vt, o, qt, b, h, Ks, Vs, &Ps[w][0]);
}

// ---------------- driver ------------------------------------------------------
extern "C" void kernel_launch(void* const* d_in, const int* in_sizes, int n_in,
                              void* d_out, int out_size, void* d_ws, size_t ws_size,
                              hipStream_t stream){
  (void)in_sizes; (void)n_in; (void)out_size;
  const int*   tok  = (const int*)d_in[0];
  const float* wte  = (const float*)d_in[1];
  const float* ln1s = (const float*)d_in[2];
  const float* ln1b = (const float*)d_in[3];
  const float* Wq   = (const float*)d_in[4];
  const float* bq   = (const float*)d_in[5];
  const float* Wk   = (const float*)d_in[6];
  const float* bk   = (const float*)d_in[7];
  const float* Wv   = (const float*)d_in[8];
  const float* bv   = (const float*)d_in[9];
  const float* Wo   = (const float*)d_in[10];
  const float* bo   = (const float*)d_in[11];
  const float* ln2s = (const float*)d_in[12];
  const float* ln2b = (const float*)d_in[13];
  const float* Wfi  = (const float*)d_in[14];
  const float* bfi  = (const float*)d_in[15];
  const float* Wfo  = (const float*)d_in[16];
  const float* bfo  = (const float*)d_in[17];
  const float* lnfs = (const float*)d_in[18];
  const float* lnfb = (const float*)d_in[19];

  char* ws = (char*)d_ws;
  float* x   = (float*)(ws);
  u16* h     = (u16*)(ws + ( 8u << 20));
  u16* qkv   = (u16*)(ws + (12u << 20));
  u16* v_t   = (u16*)(ws + (24u << 20));
  u16* attnb = (u16*)(ws + (28u << 20));
  u16* ffn   = (u16*)(ws + (32u << 20));
  u16* wT    = (u16*)(ws + (48u << 20));
  float* b3  = (float*)(ws + (56u << 20));
  u16* wteb  = (u16*)(ws + (57u << 20));

  const size_t wteb_bytes = (size_t)50257 * 1024 * 2;
  const bool big_ws = ws_size >= ((size_t)(57u) << 20) + wteb_bytes;

  if (big_ws){
    // convert wte to bf16 once (51,463,168 elems = 6,432,896 lanes of 8)
    cvt_bf16_kernel<<<25129, 256, 0, stream>>>(wte, wteb, 6432896);
  }
  embed_kernel<<<2048, 256, 0, stream>>>(tok, wte, x);
  concat_all_kernel<<<48, 256, 0, stream>>>(bq, bk, bv, b3);
  for (int i = 0; i < 4; ++i){
    ln_kernel<<<2048, 256, 0, stream>>>(x, ln1s + i*1024, ln1b + i*1024, h);
    transpose3_kernel<<<dim3(16,16,3), 256, 0, stream>>>(
        Wq + (size_t)i*1048576, Wk + (size_t)i*1048576, Wv + (size_t)i*1048576, wT);
    gemm_nt<false,128,128,2,2><<<dim3(24,16), 256, 0, stream>>>(h, wT, b3 + i*3072, qkv, nullptr, 3072, 1024, 0);
    transpose_kernel<u16><<<dim3(16,32), 256, 0, stream>>>(qkv + 2048, v_t, 3072, 2048);
    attn_kernel<<<dim3(16,32), 256, 0, stream>>>(qkv, v_t, attnb);
    transpose_kernel<float><<<dim3(16,16), 256, 0, stream>>>(Wo + (size_t)i*1048576, wT, 1024, 1024);
    gemm_nt<false,64,64,2,2><<<dim3(16,32), 256, 0, stream>>>(attnb, wT, bo + i*1024, nullptr, x, 1024, 1024, 2);
    ln_kernel<<<2048, 256, 0, stream>>>(x, ln2s + i*1024, ln2b + i*1024, h);
    transpose_kernel<float><<<dim3(64,16), 256, 0, stream>>>(Wfi + (size_t)i*4194304, wT, 4096, 1024);
    gemm_nt<false,128,256,2,4><<<dim3(16,16), 512, 0, stream>>>(h, wT, bfi + i*4096, ffn, nullptr, 4096, 1024, 1);
    transpose_kernel<float><<<dim3(16,64), 256, 0, stream>>>(Wfo + (size_t)i*4194304, wT, 1024, 4096);
    gemm_nt<false,64,64,2,2><<<dim3(16,32), 256, 0, stream>>>(ffn, wT, bfo + i*1024, nullptr, x, 1024, 4096, 2);
  }
  ln_kernel<<<2048, 256, 0, stream>>>(x, lnfs, lnfb, h);
  if (big_ws){
    gemm_nt<false,128,256,2,4><<<dim3(197,16), 512, 0, stream>>>(h, wteb, nullptr, nullptr, (float*)d_out, 50257, 1024, 3);
  } else {
    gemm_nt<true,128,128,2,2><<<dim3(393,16), 256, 0, stream>>>(h, wte, nullptr, nullptr, (float*)d_out, 50257, 1024, 3);
  }
}